// Round 2
// baseline (6397.162 us; speedup 1.0000x reference)
//
#include <hip/hip_runtime.h>

// ---------------------------------------------------------------------------
// Point-cloud Mamba pipeline, all-f32 baseline (v2: per-batch mamba stages,
// workspace footprint 46.2M floats = 176 MiB).
// Dims: N=16384 pts, D_MODEL=256, K=27, B=4, G=4096, L=12288, SEQ=49152,
// D_INNER=512, D_STATE=16, DT_RANK=16, D_CONV=4, DEPTH=2, ORDER=3.
// ---------------------------------------------------------------------------

#define NPTS  16384
#define DM    256
#define KNB   27
#define BB    4
#define GG    4096
#define LSEQ  12288
#define SEQ   49152
#define DI    512
#define DST   16
#define NCHK  96
#define LCHK  128

__device__ __forceinline__ float silu_f(float v) { return v / (1.f + __expf(-v)); }
__device__ __forceinline__ float softplus_f(float v) {
    return fmaxf(v, 0.f) + log1pf(expf(-fabsf(v)));
}
__device__ __forceinline__ float gelu_f(float v) {
    return 0.5f * v * (1.f + erff(v * 0.70710678118654752f));
}

// ---------------------------------------------------------------------------
// 1) Gather-conv: x1[n,d] = sum_{k,c} feat[nidx[n,k],c] * conv_w[k,c,d] + conv_b[d]
// ---------------------------------------------------------------------------
__global__ __launch_bounds__(256) void conv_gather_k(
    const float* __restrict__ feat, const int* __restrict__ nidx,
    const float* __restrict__ conv_w, const float* __restrict__ conv_b,
    float* __restrict__ x1)
{
    __shared__ __align__(16) float Wl[32][256];   // [c_rel][d]
    __shared__ __align__(16) float Al[32][36];    // [n_rel][c_rel]
    const int tid = threadIdx.x;
    const int n0 = blockIdx.x * 32;
    float acc[32];
#pragma unroll
    for (int i = 0; i < 32; ++i) acc[i] = 0.f;

    for (int k = 0; k < KNB; ++k) {
        for (int c0 = 0; c0 < DM; c0 += 32) {
            {
                const int row = tid >> 3;
                const int c   = (tid & 7) * 4;
                const int src = nidx[(n0 + row) * KNB + k];
                *(float4*)&Al[row][c] = *(const float4*)&feat[src * DM + c0 + c];
            }
            for (int cc = 0; cc < 32; ++cc)
                Wl[cc][tid] = conv_w[(k * DM + c0 + cc) * DM + tid];
            __syncthreads();
#pragma unroll 2
            for (int c = 0; c < 32; c += 4) {
                const float w0 = Wl[c + 0][tid];
                const float w1 = Wl[c + 1][tid];
                const float w2 = Wl[c + 2][tid];
                const float w3 = Wl[c + 3][tid];
#pragma unroll
                for (int i = 0; i < 32; ++i) {
                    const float4 a = *(const float4*)&Al[i][c];
                    acc[i] = fmaf(a.x, w0, fmaf(a.y, w1, fmaf(a.z, w2, fmaf(a.w, w3, acc[i]))));
                }
            }
            __syncthreads();
        }
    }
    const float bias = conv_b[tid];
#pragma unroll
    for (int i = 0; i < 32; ++i)
        x1[(n0 + i) * DM + tid] = acc[i] + bias;
}

// ---------------------------------------------------------------------------
// 2) Generic f32 GEMM: C[m,j] = sum_c A[m,c]*W[j,c] (+bias). 64x64 tile.
//    col-split output (out1 for col<split, out2 after). M%64==0, K%16==0.
// ---------------------------------------------------------------------------
__global__ __launch_bounds__(256) void gemm_tn(
    const float* __restrict__ A, int lda,
    const float* __restrict__ W, int ldw,
    const float* __restrict__ bias,
    float* __restrict__ out1, int ld1,
    float* __restrict__ out2, int ld2, int split,
    int M, int N, int K)
{
    __shared__ __align__(16) float As[16][68];
    __shared__ __align__(16) float Bs[16][68];
    const int tid = threadIdx.x;
    const int tx = tid & 15, ty = tid >> 4;
    const int m0 = blockIdx.x * 64, n0 = blockIdx.y * 64;
    float acc[4][4];
#pragma unroll
    for (int i = 0; i < 4; ++i)
#pragma unroll
        for (int j = 0; j < 4; ++j) acc[i][j] = 0.f;

    for (int k0 = 0; k0 < K; k0 += 16) {
#pragma unroll
        for (int r = 0; r < 4; ++r) {
            const int idx = r * 256 + tid;
            const int kk = idx & 15;
            const int row = idx >> 4;
            As[kk][row] = A[(m0 + row) * lda + k0 + kk];
            Bs[kk][row] = (n0 + row < N) ? W[(n0 + row) * ldw + k0 + kk] : 0.f;
        }
        __syncthreads();
#pragma unroll
        for (int kk = 0; kk < 16; ++kk) {
            const float4 a4 = *(const float4*)&As[kk][ty * 4];
            const float4 b4 = *(const float4*)&Bs[kk][tx * 4];
            float av[4] = {a4.x, a4.y, a4.z, a4.w};
            float bv[4] = {b4.x, b4.y, b4.z, b4.w};
#pragma unroll
            for (int i = 0; i < 4; ++i)
#pragma unroll
                for (int j = 0; j < 4; ++j)
                    acc[i][j] = fmaf(av[i], bv[j], acc[i][j]);
        }
        __syncthreads();
    }
    const int col = n0 + tx * 4;
    if (col < N) {
        float4 b4 = make_float4(0.f, 0.f, 0.f, 0.f);
        if (bias) b4 = *(const float4*)&bias[col];
#pragma unroll
        for (int i = 0; i < 4; ++i) {
            const int row = m0 + ty * 4 + i;
            float4 v;
            v.x = acc[i][0] + b4.x; v.y = acc[i][1] + b4.y;
            v.z = acc[i][2] + b4.z; v.w = acc[i][3] + b4.w;
            if (col < split) *(float4*)&out1[row * ld1 + col] = v;
            else             *(float4*)&out2[row * ld2 + col - split] = v;
        }
    }
}

// ---------------------------------------------------------------------------
// 3) LayerNorm over 256 cols (+optional residual add, +optional gelu)
// ---------------------------------------------------------------------------
__global__ __launch_bounds__(256) void ln_k(
    const float* __restrict__ in, const float* __restrict__ add,
    float* __restrict__ out,
    const float* __restrict__ s, const float* __restrict__ b, int do_gelu)
{
    const int wid = threadIdx.x >> 6, lane = threadIdx.x & 63;
    const int row = blockIdx.x * 4 + wid;
    const int base = row * DM + lane * 4;
    const float4 x4 = *(const float4*)&in[base];
    float sum = x4.x + x4.y + x4.z + x4.w;
#pragma unroll
    for (int off = 32; off > 0; off >>= 1) sum += __shfl_xor(sum, off, 64);
    const float mean = sum * 0.00390625f;
    const float d0 = x4.x - mean, d1 = x4.y - mean, d2 = x4.z - mean, d3 = x4.w - mean;
    float vs = d0 * d0 + d1 * d1 + d2 * d2 + d3 * d3;
#pragma unroll
    for (int off = 32; off > 0; off >>= 1) vs += __shfl_xor(vs, off, 64);
    const float rstd = rsqrtf(vs * 0.00390625f + 1e-5f);
    const float4 s4 = *(const float4*)&s[lane * 4];
    const float4 b4 = *(const float4*)&b[lane * 4];
    float o0 = d0 * rstd * s4.x + b4.x;
    float o1 = d1 * rstd * s4.y + b4.y;
    float o2 = d2 * rstd * s4.z + b4.z;
    float o3 = d3 * rstd * s4.w + b4.w;
    if (add) {
        const float4 a4 = *(const float4*)&add[base];
        o0 += a4.x; o1 += a4.y; o2 += a4.z; o3 += a4.w;
    }
    if (do_gelu) { o0 = gelu_f(o0); o1 = gelu_f(o1); o2 = gelu_f(o2); o3 = gelu_f(o3); }
    float4 r; r.x = o0; r.y = o1; r.z = o2; r.w = o3;
    *(float4*)&out[base] = r;
}

// ---------------------------------------------------------------------------
// 4) Serialize: RES[b*L + o*G + g, :] = X3[inverse[o, b*G+g], :]
// ---------------------------------------------------------------------------
__global__ __launch_bounds__(256) void serialize_k(
    const float* __restrict__ x3, const int* __restrict__ inv,
    float* __restrict__ res)
{
    const int wid = threadIdx.x >> 6, lane = threadIdx.x & 63;
    const int r = blockIdx.x * 4 + wid;
    const int b = r / LSEQ, l = r % LSEQ;
    const int o = l >> 12, g = l & 4095;
    const int src = inv[o * NPTS + b * GG + g];
    *(float4*)&res[r * DM + lane * 4] = *(const float4*)&x3[src * DM + lane * 4];
}

// Deserialize+regroup: H3[n, o*256+d] = RES[(m>>12)*L + o*G + (m&4095), d], m=order[o,n]
__global__ __launch_bounds__(256) void deserialize_k(
    const float* __restrict__ res, const int* __restrict__ order,
    float* __restrict__ h3)
{
    const int wid = threadIdx.x >> 6, lane = threadIdx.x & 63;
    const int p = blockIdx.x * 4 + wid;       // 0..49151
    const int o = p >> 14, n = p & 16383;
    const int m = order[o * NPTS + n];
    const int bp = m >> 12, gp = m & 4095;
    const int srow = bp * LSEQ + o * GG + gp;
    *(float4*)&h3[n * 768 + o * DM + lane * 4] = *(const float4*)&res[srow * DM + lane * 4];
}

// a += c  (count*4 floats)
__global__ __launch_bounds__(256) void add_k(float* __restrict__ a, const float* __restrict__ c)
{
    const int i = (blockIdx.x * 256 + threadIdx.x) * 4;
    float4 x = *(float4*)&a[i];
    const float4 y = *(const float4*)&c[i];
    x.x += y.x; x.y += y.y; x.z += y.z; x.w += y.w;
    *(float4*)&a[i] = x;
}

// ---------------------------------------------------------------------------
// 5) Depthwise causal conv1d (4 taps) + bias + silu.  Per-b input (L rows).
// ---------------------------------------------------------------------------
__global__ __launch_bounds__(256) void conv1d_silu_k(
    const float* __restrict__ xh, const float* __restrict__ cw,
    const float* __restrict__ cb, float* __restrict__ xc)
{
    const int gidx = blockIdx.x * 256 + threadIdx.x;     // LSEQ*128
    const int t = gidx >> 7;
    const int e4 = (gidx & 127) << 2;
    float wta[4][4];
#pragma unroll
    for (int ee = 0; ee < 4; ++ee) {
        const float4 wv = *(const float4*)&cw[(e4 + ee) * 4];
        wta[ee][0] = wv.x; wta[ee][1] = wv.y; wta[ee][2] = wv.z; wta[ee][3] = wv.w;
    }
    const float4 c4 = *(const float4*)&cb[e4];
    float a[4] = {c4.x, c4.y, c4.z, c4.w};
#pragma unroll
    for (int j = 0; j < 4; ++j) {
        const int tt = t - 3 + j;
        if (tt >= 0) {
            const float4 x4 = *(const float4*)&xh[tt * DI + e4];
            a[0] = fmaf(x4.x, wta[0][j], a[0]);
            a[1] = fmaf(x4.y, wta[1][j], a[1]);
            a[2] = fmaf(x4.z, wta[2][j], a[2]);
            a[3] = fmaf(x4.w, wta[3][j], a[3]);
        }
    }
    float4 rr;
    rr.x = silu_f(a[0]); rr.y = silu_f(a[1]); rr.z = silu_f(a[2]); rr.w = silu_f(a[3]);
    *(float4*)&xc[t * DI + e4] = rr;
}

// ---------------------------------------------------------------------------
// 6) Chunked selective scan (per-b). CHUNK=128, 96 chunks, dt_proj fused.
// ---------------------------------------------------------------------------
__global__ __launch_bounds__(256) void scan_pass1_k(
    const float* __restrict__ xc, const float* __restrict__ dbc,
    const float* __restrict__ dtw_all, const float* __restrict__ dtb_all,
    const float* __restrict__ alog_all,
    float* __restrict__ PA, float* __restrict__ HB, int layer)
{
    const int bid = blockIdx.x;            // NCHK*2
    const int half = bid & 1;
    const int ci = bid >> 1;
    const int e = half * 256 + threadIdx.x;
    float w[DST], A[DST];
    const float* dtw = dtw_all + layer * (DI * DST) + e * DST;
    const float* al  = alog_all + layer * (DI * DST) + e * DST;
#pragma unroll
    for (int r = 0; r < DST; ++r) w[r] = dtw[r];
#pragma unroll
    for (int n = 0; n < DST; ++n) A[n] = -expf(al[n]) * 1.4426950408889634f;
    const float dtb = dtb_all[layer * DI + e];
    __shared__ __align__(16) float dl[LCHK][48];
    const int row0 = ci * LCHK;
    for (int i = threadIdx.x; i < LCHK * 48; i += 256)
        ((float*)dl)[i] = dbc[row0 * 48 + i];
    __syncthreads();
    float h[DST], pa[DST];
#pragma unroll
    for (int n = 0; n < DST; ++n) { h[n] = 0.f; pa[n] = 1.f; }
    for (int t = 0; t < LCHK; ++t) {
        float dtr = dtb;
#pragma unroll
        for (int r = 0; r < DST; ++r) dtr = fmaf(dl[t][r], w[r], dtr);
        const float dt = softplus_f(dtr);
        const float x = xc[(row0 + t) * DI + e];
        const float dx = dt * x;
#pragma unroll
        for (int n = 0; n < DST; ++n) {
            const float E = exp2f(dt * A[n]);
            h[n] = fmaf(h[n], E, dx * dl[t][16 + n]);
            pa[n] *= E;
        }
    }
    const int off = (ci * DI + e) * DST;
#pragma unroll
    for (int n = 0; n < DST; ++n) { PA[off + n] = pa[n]; HB[off + n] = h[n]; }
}

__global__ __launch_bounds__(256) void scan_pass2_k(
    const float* __restrict__ PA, float* __restrict__ HB)
{
    const int idx = blockIdx.x * 256 + threadIdx.x;   // < 8192
    float h = 0.f;
    for (int ci = 0; ci < NCHK; ++ci) {
        const int off = ci * 8192 + idx;
        const float pa = PA[off];
        const float hb = HB[off];
        const float nh = fmaf(h, pa, hb);
        HB[off] = h;          // exclusive chunk-input state
        h = nh;
    }
}

__global__ __launch_bounds__(256) void scan_pass3_k(
    const float* __restrict__ xc, const float* __restrict__ dbc,
    const float* __restrict__ dtw_all, const float* __restrict__ dtb_all,
    const float* __restrict__ alog_all, const float* __restrict__ dsk_all,
    const float* __restrict__ HB, const float* __restrict__ Z,
    float* __restrict__ Y, int layer)
{
    const int bid = blockIdx.x;
    const int half = bid & 1;
    const int ci = bid >> 1;
    const int e = half * 256 + threadIdx.x;
    float w[DST], A[DST];
    const float* dtw = dtw_all + layer * (DI * DST) + e * DST;
    const float* al  = alog_all + layer * (DI * DST) + e * DST;
#pragma unroll
    for (int r = 0; r < DST; ++r) w[r] = dtw[r];
#pragma unroll
    for (int n = 0; n < DST; ++n) A[n] = -expf(al[n]) * 1.4426950408889634f;
    const float dtb = dtb_all[layer * DI + e];
    const float dsk = dsk_all[layer * DI + e];
    __shared__ __align__(16) float dl[LCHK][48];
    const int row0 = ci * LCHK;
    for (int i = threadIdx.x; i < LCHK * 48; i += 256)
        ((float*)dl)[i] = dbc[row0 * 48 + i];
    __syncthreads();
    const int off = (ci * DI + e) * DST;
    float h[DST];
#pragma unroll
    for (int n = 0; n < DST; ++n) h[n] = HB[off + n];
    for (int t = 0; t < LCHK; ++t) {
        float dtr = dtb;
#pragma unroll
        for (int r = 0; r < DST; ++r) dtr = fmaf(dl[t][r], w[r], dtr);
        const float dt = softplus_f(dtr);
        const float x = xc[(row0 + t) * DI + e];
        const float dx = dt * x;
        float y = 0.f;
#pragma unroll
        for (int n = 0; n < DST; ++n) {
            const float E = exp2f(dt * A[n]);
            h[n] = fmaf(h[n], E, dx * dl[t][16 + n]);
            y = fmaf(h[n], dl[t][32 + n], y);
        }
        y = fmaf(x, dsk, y);
        const float z = Z[(row0 + t) * DI + e];
        Y[(row0 + t) * DI + e] = y * silu_f(z);
    }
}

// ---------------------------------------------------------------------------
// Launch
// ---------------------------------------------------------------------------
extern "C" void kernel_launch(void* const* d_in, const int* in_sizes, int n_in,
                              void* d_out, int out_size, void* d_ws, size_t ws_size,
                              hipStream_t stream) {
    (void)in_sizes; (void)n_in; (void)out_size; (void)ws_size;
    const float* feat     = (const float*)d_in[0];
    const int*   nidx     = (const int*)d_in[1];
    const int*   order    = (const int*)d_in[2];
    const int*   inv      = (const int*)d_in[3];
    const float* conv_w   = (const float*)d_in[5];
    const float* conv_b   = (const float*)d_in[6];
    const float* cpe_fc_w = (const float*)d_in[7];
    const float* cpe_fc_b = (const float*)d_in[8];
    const float* cpe_ln_s = (const float*)d_in[9];
    const float* cpe_ln_b = (const float*)d_in[10];
    const float* in_proj_w = (const float*)d_in[11];
    const float* conv1d_w  = (const float*)d_in[12];
    const float* conv1d_b  = (const float*)d_in[13];
    const float* x_proj_w  = (const float*)d_in[14];
    const float* dt_proj_w = (const float*)d_in[15];
    const float* dt_proj_b = (const float*)d_in[16];
    const float* A_log     = (const float*)d_in[17];
    const float* D_skip    = (const float*)d_in[18];
    const float* out_proj_w = (const float*)d_in[19];
    const float* blk_ln_s  = (const float*)d_in[20];
    const float* blk_ln_b  = (const float*)d_in[21];
    const float* normf_s   = (const float*)d_in[22];
    const float* normf_b   = (const float*)d_in[23];
    const float* fuse_w1   = (const float*)d_in[24];
    const float* fuse_b1   = (const float*)d_in[25];
    const float* fuse_ln_s = (const float*)d_in[26];
    const float* fuse_ln_b = (const float*)d_in[27];
    const float* fuse_w2   = (const float*)d_in[28];
    const float* fuse_b2   = (const float*)d_in[29];
    float* out = (float*)d_out;
    float* ws = (float*)d_ws;

    // workspace layout (floats); total 46,202,880 floats = 176.3 MiB
    float* RES  = ws;                       // 49152*256          = 12,582,912
    float* BUF1 = RES  + 12582912;          // 12,582,912 (XHb/Y 6.29M | H3 12.58M | X1 4.19M)
    float* BUF2 = BUF1 + 12582912;          //  6,291,456 (Zb | X2 | F1)
    float* BUF3 = BUF2 + 6291456;           //  6,291,456 (XCb | X1' | F2)
    float* HSLb = BUF3 + 6291456;           //  3,145,728 (12288*256)
    float* DBCb = HSLb + 3145728;           //    589,824 (12288*48)
    float* PAb  = DBCb + 589824;            //    786,432 (96*512*16)
    float* HBb  = PAb  + 786432;            //    786,432
    float* MOb  = HBb  + 786432;            //  3,145,728 (12288*256)

    const int BIG = 1 << 30;

    // ---- CPE ----
    conv_gather_k<<<NPTS / 32, 256, 0, stream>>>(feat, nidx, conv_w, conv_b, BUF1);
    gemm_tn<<<dim3(NPTS / 64, 4), 256, 0, stream>>>(BUF1, DM, cpe_fc_w, DM, cpe_fc_b,
                                                    BUF2, DM, nullptr, 0, BIG, NPTS, DM, DM);
    ln_k<<<NPTS / 4, 256, 0, stream>>>(BUF2, feat, BUF3, cpe_ln_s, cpe_ln_b, 0);
    serialize_k<<<SEQ / 4, 256, 0, stream>>>(BUF3, inv, RES);

    // ---- Mamba blocks (per layer, per batch element) ----
    for (int l = 0; l < 2; ++l) {
        for (int b = 0; b < BB; ++b) {
            const float* RESb = RES + (size_t)b * LSEQ * DM;
            ln_k<<<LSEQ / 4, 256, 0, stream>>>(RESb, nullptr, HSLb,
                                               blk_ln_s + l * DM, blk_ln_b + l * DM, 0);
            gemm_tn<<<dim3(LSEQ / 64, 16), 256, 0, stream>>>(HSLb, DM, in_proj_w + l * 262144, DM,
                                                             nullptr, BUF1, DI, BUF2, DI, DI,
                                                             LSEQ, 1024, DM);
            conv1d_silu_k<<<LSEQ * 128 / 256, 256, 0, stream>>>(BUF1, conv1d_w + l * 2048,
                                                                conv1d_b + l * DI, BUF3);
            gemm_tn<<<dim3(LSEQ / 64, 1), 256, 0, stream>>>(BUF3, DI, x_proj_w + l * 24576, DI,
                                                            nullptr, DBCb, 48, nullptr, 0, BIG,
                                                            LSEQ, 48, DI);
            scan_pass1_k<<<NCHK * 2, 256, 0, stream>>>(BUF3, DBCb, dt_proj_w, dt_proj_b, A_log,
                                                       PAb, HBb, l);
            scan_pass2_k<<<32, 256, 0, stream>>>(PAb, HBb);
            scan_pass3_k<<<NCHK * 2, 256, 0, stream>>>(BUF3, DBCb, dt_proj_w, dt_proj_b, A_log,
                                                       D_skip, HBb, BUF2, BUF1 /*Y*/, l);
            gemm_tn<<<dim3(LSEQ / 64, 4), 256, 0, stream>>>(BUF1, DI, out_proj_w + l * 131072, DI,
                                                            nullptr, MOb, DM, nullptr, 0, BIG,
                                                            LSEQ, DM, DI);
            add_k<<<LSEQ * DM / 1024, 256, 0, stream>>>(RES + (size_t)b * LSEQ * DM, MOb);
        }
    }

    // ---- Final: deserialize, then row-wise LN (commutes with permutation) ----
    deserialize_k<<<SEQ / 4, 256, 0, stream>>>(RES, order, BUF1 /*H3: 16384x768*/);
    ln_k<<<SEQ / 4, 256, 0, stream>>>(BUF1, nullptr, BUF1, normf_s, normf_b, 0);  // in-place per 256-seg
    gemm_tn<<<dim3(NPTS / 64, 4), 256, 0, stream>>>(BUF1, 768, fuse_w1, 768, fuse_b1,
                                                    BUF2, DM, nullptr, 0, BIG, NPTS, DM, 768);
    ln_k<<<NPTS / 4, 256, 0, stream>>>(BUF2, nullptr, BUF3, fuse_ln_s, fuse_ln_b, 1);
    gemm_tn<<<dim3(NPTS / 64, 4), 256, 0, stream>>>(BUF3, DM, fuse_w2, DM, fuse_b2,
                                                    out, DM, nullptr, 0, BIG, NPTS, DM, DM);
}

// Round 3
// 3384.261 us; speedup vs baseline: 1.8903x; 1.8903x over previous
//
#include <hip/hip_runtime.h>
#include <hip/hip_bf16.h>

// ---------------------------------------------------------------------------
// Point-cloud Mamba pipeline, v3: bf16 MFMA for the 5 heavy GEMMs
// (gather-conv, in_proj, x_proj, out_proj, fuse1), f32 elsewhere.
// Dims: N=16384 pts, D_MODEL=256, K=27, B=4, L=12288, SEQ=49152,
// D_INNER=512, D_STATE=16, DT_RANK=16, DEPTH=2, ORDER=3.
// Workspace: 38,690,816 floats = 147.6 MiB.
// ---------------------------------------------------------------------------

#define NPTS  16384
#define DM    256
#define KNB   27
#define BB    4
#define GG    4096
#define LSEQ  12288
#define SEQ   49152
#define DI    512
#define DST   16
#define NCHK  96
#define LCHK  128

typedef unsigned short ushort;
typedef __attribute__((ext_vector_type(8))) short short8;
typedef __attribute__((ext_vector_type(4))) float f32x4;

__device__ __forceinline__ float silu_f(float v) { return v / (1.f + __expf(-v)); }
__device__ __forceinline__ float softplus_f(float v) {
    return fmaxf(v, 0.f) + log1pf(expf(-fabsf(v)));
}
__device__ __forceinline__ float gelu_f(float v) {
    return 0.5f * v * (1.f + erff(v * 0.70710678118654752f));
}
__device__ __forceinline__ ushort f2b(float f) {
    __hip_bfloat16 h = __float2bfloat16(f);
    return __builtin_bit_cast(ushort, h);
}
__device__ __forceinline__ float b2f(ushort u) {
    unsigned int x = ((unsigned int)u) << 16;
    return __builtin_bit_cast(float, x);
}

// ---------------------------------------------------------------------------
// f32 -> bf16 convert (grid-stride)
// ---------------------------------------------------------------------------
__global__ __launch_bounds__(256) void f2b_k(const float* __restrict__ in,
                                             ushort* __restrict__ out, int n)
{
    for (int i = blockIdx.x * 256 + threadIdx.x; i < n; i += gridDim.x * 256)
        out[i] = f2b(in[i]);
}

// conv_w [27*256][256] -> W2 bf16 [256][6912] (transpose + convert)
__global__ __launch_bounds__(256) void transpose_convw_k(
    const float* __restrict__ cw, ushort* __restrict__ w2)
{
    __shared__ float T[32][33];
    const int kc0 = blockIdx.x * 32, d0 = blockIdx.y * 32;
    const int j = threadIdx.x & 31, r0 = (threadIdx.x >> 5) * 4;
#pragma unroll
    for (int r = 0; r < 4; ++r)
        T[r0 + r][j] = cw[(kc0 + r0 + r) * 256 + d0 + j];
    __syncthreads();
    const int i2 = threadIdx.x & 31;
#pragma unroll
    for (int r = 0; r < 4; ++r)
        w2[(d0 + r0 + r) * (KNB * DM) + kc0 + i2] = f2b(T[i2][r0 + r]);
}

// ---------------------------------------------------------------------------
// bf16 MFMA GEMM: C[m,j] = sum_c A[m,c]*W[j,c] (+bias). A,W bf16; C f32.
// Tile 64x64, BK=64, 4 waves (wave w owns rows w*16..w*16+15).
// LDS XOR swizzle: granule col8 ^= (row&7). split: col<split->out1 else out2.
// accum: out1 += result. M%64==0, K%64==0. N bounds-checked.
// ---------------------------------------------------------------------------
__global__ __launch_bounds__(256) void gemm_bf(
    const ushort* __restrict__ A, int lda,
    const ushort* __restrict__ W, int ldw,
    const float* __restrict__ bias,
    float* __restrict__ out1, int ld1,
    float* __restrict__ out2, int ld2, int split,
    int N, int K, int accum)
{
    __shared__ __align__(16) ushort As[64 * 64];
    __shared__ __align__(16) ushort Bs[64 * 64];
    const int tid = threadIdx.x;
    const int w = tid >> 6, lane = tid & 63;
    const int m0 = blockIdx.x * 64, n0 = blockIdx.y * 64;
    f32x4 acc[4];
#pragma unroll
    for (int i = 0; i < 4; ++i) acc[i] = (f32x4){0.f, 0.f, 0.f, 0.f};

    for (int k0 = 0; k0 < K; k0 += 64) {
#pragma unroll
        for (int rr = 0; rr < 2; ++rr) {
            const int g = rr * 256 + tid;
            const int row = g >> 3, c8 = g & 7;
            const int phys = row * 64 + ((c8 ^ (row & 7)) << 3);
            *(short8*)&As[phys] = *(const short8*)&A[(m0 + row) * lda + k0 + c8 * 8];
            short8 bv = (short8){0,0,0,0,0,0,0,0};
            if (n0 + row < N) bv = *(const short8*)&W[(n0 + row) * ldw + k0 + c8 * 8];
            *(short8*)&Bs[phys] = bv;
        }
        __syncthreads();
#pragma unroll
        for (int kk = 0; kk < 2; ++kk) {
            const int row_a = w * 16 + (lane & 15);
            const int c8a = kk * 4 + (lane >> 4);
            const short8 av = *(const short8*)&As[row_a * 64 + ((c8a ^ (row_a & 7)) << 3)];
#pragma unroll
            for (int cf = 0; cf < 4; ++cf) {
                const int row_b = cf * 16 + (lane & 15);
                const short8 bv = *(const short8*)&Bs[row_b * 64 + ((c8a ^ (row_b & 7)) << 3)];
                acc[cf] = __builtin_amdgcn_mfma_f32_16x16x32_bf16(av, bv, acc[cf], 0, 0, 0);
            }
        }
        __syncthreads();
    }
    const int rbase = m0 + w * 16 + ((lane >> 4) << 2);
#pragma unroll
    for (int cf = 0; cf < 4; ++cf) {
        const int col = n0 + cf * 16 + (lane & 15);
        if (col < N) {
            const float bb = bias ? bias[col] : 0.f;
#pragma unroll
            for (int r = 0; r < 4; ++r) {
                const float v = acc[cf][r] + bb;
                const int row = rbase + r;
                if (accum)           out1[row * ld1 + col] += v;
                else if (col < split) out1[row * ld1 + col] = v;
                else                  out2[row * ld2 + (col - split)] = v;
            }
        }
    }
}

// ---------------------------------------------------------------------------
// Gathered-A bf16 GEMM (gather-conv):
// X1[n,d] = sum_{k,c} featb[nidx[n,k],c] * W2[d, k*256+c] + conv_b[d]
// Tile 64(n) x 64(d), K=6912 in BK=64 steps.
// ---------------------------------------------------------------------------
__global__ __launch_bounds__(256) void gather_bf(
    const ushort* __restrict__ featb, const int* __restrict__ nidx,
    const ushort* __restrict__ w2, const float* __restrict__ bias,
    float* __restrict__ out)
{
    __shared__ __align__(16) ushort As[64 * 64];
    __shared__ __align__(16) ushort Bs[64 * 64];
    __shared__ int idxs[64 * 28];
    const int tid = threadIdx.x;
    const int w = tid >> 6, lane = tid & 63;
    const int m0 = blockIdx.x * 64, n0 = blockIdx.y * 64;
    for (int i = tid; i < 64 * KNB; i += 256) {
        const int row = i / KNB, kk = i - row * KNB;
        idxs[row * 28 + kk] = nidx[(m0 + row) * KNB + kk];
    }
    __syncthreads();
    f32x4 acc[4];
#pragma unroll
    for (int i = 0; i < 4; ++i) acc[i] = (f32x4){0.f, 0.f, 0.f, 0.f};

    for (int k0 = 0; k0 < KNB * DM; k0 += 64) {
        const int kt = k0 >> 8, c0 = k0 & 255;
#pragma unroll
        for (int rr = 0; rr < 2; ++rr) {
            const int g = rr * 256 + tid;
            const int row = g >> 3, c8 = g & 7;
            const int phys = row * 64 + ((c8 ^ (row & 7)) << 3);
            const int src = idxs[row * 28 + kt];
            *(short8*)&As[phys] = *(const short8*)&featb[src * DM + c0 + c8 * 8];
            *(short8*)&Bs[phys] = *(const short8*)&w2[(n0 + row) * (KNB * DM) + k0 + c8 * 8];
        }
        __syncthreads();
#pragma unroll
        for (int kk = 0; kk < 2; ++kk) {
            const int row_a = w * 16 + (lane & 15);
            const int c8a = kk * 4 + (lane >> 4);
            const short8 av = *(const short8*)&As[row_a * 64 + ((c8a ^ (row_a & 7)) << 3)];
#pragma unroll
            for (int cf = 0; cf < 4; ++cf) {
                const int row_b = cf * 16 + (lane & 15);
                const short8 bv = *(const short8*)&Bs[row_b * 64 + ((c8a ^ (row_b & 7)) << 3)];
                acc[cf] = __builtin_amdgcn_mfma_f32_16x16x32_bf16(av, bv, acc[cf], 0, 0, 0);
            }
        }
        __syncthreads();
    }
    const int rbase = m0 + w * 16 + ((lane >> 4) << 2);
#pragma unroll
    for (int cf = 0; cf < 4; ++cf) {
        const int col = n0 + cf * 16 + (lane & 15);
        const float bb = bias[col];
#pragma unroll
        for (int r = 0; r < 4; ++r)
            out[(rbase + r) * DM + col] = acc[cf][r] + bb;
    }
}

// ---------------------------------------------------------------------------
// f32 GEMM (cpe, fuse2): C[m,j] = sum_c A[m,c]*W[j,c] (+bias). 64x64 tile.
// ---------------------------------------------------------------------------
__global__ __launch_bounds__(256) void gemm_tn(
    const float* __restrict__ A, int lda,
    const float* __restrict__ W, int ldw,
    const float* __restrict__ bias,
    float* __restrict__ out1, int ld1, int N, int K)
{
    __shared__ __align__(16) float As[16][68];
    __shared__ __align__(16) float Bs[16][68];
    const int tid = threadIdx.x;
    const int tx = tid & 15, ty = tid >> 4;
    const int m0 = blockIdx.x * 64, n0 = blockIdx.y * 64;
    float acc[4][4];
#pragma unroll
    for (int i = 0; i < 4; ++i)
#pragma unroll
        for (int j = 0; j < 4; ++j) acc[i][j] = 0.f;

    for (int k0 = 0; k0 < K; k0 += 16) {
#pragma unroll
        for (int r = 0; r < 4; ++r) {
            const int idx = r * 256 + tid;
            const int kk = idx & 15;
            const int row = idx >> 4;
            As[kk][row] = A[(m0 + row) * lda + k0 + kk];
            Bs[kk][row] = (n0 + row < N) ? W[(n0 + row) * ldw + k0 + kk] : 0.f;
        }
        __syncthreads();
#pragma unroll
        for (int kk = 0; kk < 16; ++kk) {
            const float4 a4 = *(const float4*)&As[kk][ty * 4];
            const float4 b4 = *(const float4*)&Bs[kk][tx * 4];
            float av[4] = {a4.x, a4.y, a4.z, a4.w};
            float bv[4] = {b4.x, b4.y, b4.z, b4.w};
#pragma unroll
            for (int i = 0; i < 4; ++i)
#pragma unroll
                for (int j = 0; j < 4; ++j)
                    acc[i][j] = fmaf(av[i], bv[j], acc[i][j]);
        }
        __syncthreads();
    }
    const int col = n0 + tx * 4;
    if (col < N) {
        float4 b4 = make_float4(0.f, 0.f, 0.f, 0.f);
        if (bias) b4 = *(const float4*)&bias[col];
#pragma unroll
        for (int i = 0; i < 4; ++i) {
            const int row = m0 + ty * 4 + i;
            float4 v;
            v.x = acc[i][0] + b4.x; v.y = acc[i][1] + b4.y;
            v.z = acc[i][2] + b4.z; v.w = acc[i][3] + b4.w;
            *(float4*)&out1[row * ld1 + col] = v;
        }
    }
}

// ---------------------------------------------------------------------------
// LayerNorm over 256 cols (+optional residual add, +gelu, +bf16 out)
// ---------------------------------------------------------------------------
__global__ __launch_bounds__(256) void ln_k(
    const float* __restrict__ in, const float* __restrict__ add,
    void* __restrict__ outp,
    const float* __restrict__ s, const float* __restrict__ b,
    int do_gelu, int obf)
{
    const int wid = threadIdx.x >> 6, lane = threadIdx.x & 63;
    const int row = blockIdx.x * 4 + wid;
    const int base = row * DM + lane * 4;
    const float4 x4 = *(const float4*)&in[base];
    float sum = x4.x + x4.y + x4.z + x4.w;
#pragma unroll
    for (int off = 32; off > 0; off >>= 1) sum += __shfl_xor(sum, off, 64);
    const float mean = sum * 0.00390625f;
    const float d0 = x4.x - mean, d1 = x4.y - mean, d2 = x4.z - mean, d3 = x4.w - mean;
    float vs = d0 * d0 + d1 * d1 + d2 * d2 + d3 * d3;
#pragma unroll
    for (int off = 32; off > 0; off >>= 1) vs += __shfl_xor(vs, off, 64);
    const float rstd = rsqrtf(vs * 0.00390625f + 1e-5f);
    const float4 s4 = *(const float4*)&s[lane * 4];
    const float4 b4 = *(const float4*)&b[lane * 4];
    float o0 = d0 * rstd * s4.x + b4.x;
    float o1 = d1 * rstd * s4.y + b4.y;
    float o2 = d2 * rstd * s4.z + b4.z;
    float o3 = d3 * rstd * s4.w + b4.w;
    if (add) {
        const float4 a4 = *(const float4*)&add[base];
        o0 += a4.x; o1 += a4.y; o2 += a4.z; o3 += a4.w;
    }
    if (do_gelu) { o0 = gelu_f(o0); o1 = gelu_f(o1); o2 = gelu_f(o2); o3 = gelu_f(o3); }
    if (obf) {
        ushort4 r; r.x = f2b(o0); r.y = f2b(o1); r.z = f2b(o2); r.w = f2b(o3);
        *(ushort4*)&((ushort*)outp)[base] = r;
    } else {
        float4 r; r.x = o0; r.y = o1; r.z = o2; r.w = o3;
        *(float4*)&((float*)outp)[base] = r;
    }
}

// ---------------------------------------------------------------------------
// Serialize: RES[b*L + o*G + g, :] = X3[inverse[o, b*G+g], :]
// ---------------------------------------------------------------------------
__global__ __launch_bounds__(256) void serialize_k(
    const float* __restrict__ x3, const int* __restrict__ inv,
    float* __restrict__ res)
{
    const int wid = threadIdx.x >> 6, lane = threadIdx.x & 63;
    const int r = blockIdx.x * 4 + wid;
    const int b = r / LSEQ, l = r % LSEQ;
    const int o = l >> 12, g = l & 4095;
    const int src = inv[o * NPTS + b * GG + g];
    *(float4*)&res[r * DM + lane * 4] = *(const float4*)&x3[src * DM + lane * 4];
}

// Deserialize+regroup: H3[n, o*256+d] = RES[(m>>12)*L + o*G + (m&4095), d], m=order[o,n]
__global__ __launch_bounds__(256) void deserialize_k(
    const float* __restrict__ res, const int* __restrict__ order,
    float* __restrict__ h3)
{
    const int wid = threadIdx.x >> 6, lane = threadIdx.x & 63;
    const int p = blockIdx.x * 4 + wid;       // 0..49151
    const int o = p >> 14, n = p & 16383;
    const int m = order[o * NPTS + n];
    const int bp = m >> 12, gp = m & 4095;
    const int srow = bp * LSEQ + o * GG + gp;
    *(float4*)&h3[n * 768 + o * DM + lane * 4] = *(const float4*)&res[srow * DM + lane * 4];
}

// ---------------------------------------------------------------------------
// Depthwise causal conv1d (4 taps) + bias + silu. f32 in, bf16 out. Per-b.
// ---------------------------------------------------------------------------
__global__ __launch_bounds__(256) void conv1d_silu_k(
    const float* __restrict__ xh, const float* __restrict__ cw,
    const float* __restrict__ cb, ushort* __restrict__ xcb)
{
    const int gidx = blockIdx.x * 256 + threadIdx.x;     // LSEQ*128
    const int t = gidx >> 7;
    const int e4 = (gidx & 127) << 2;
    float wta[4][4];
#pragma unroll
    for (int ee = 0; ee < 4; ++ee) {
        const float4 wv = *(const float4*)&cw[(e4 + ee) * 4];
        wta[ee][0] = wv.x; wta[ee][1] = wv.y; wta[ee][2] = wv.z; wta[ee][3] = wv.w;
    }
    const float4 c4 = *(const float4*)&cb[e4];
    float a[4] = {c4.x, c4.y, c4.z, c4.w};
#pragma unroll
    for (int j = 0; j < 4; ++j) {
        const int tt = t - 3 + j;
        if (tt >= 0) {
            const float4 x4 = *(const float4*)&xh[tt * DI + e4];
            a[0] = fmaf(x4.x, wta[0][j], a[0]);
            a[1] = fmaf(x4.y, wta[1][j], a[1]);
            a[2] = fmaf(x4.z, wta[2][j], a[2]);
            a[3] = fmaf(x4.w, wta[3][j], a[3]);
        }
    }
    ushort4 rr;
    rr.x = f2b(silu_f(a[0])); rr.y = f2b(silu_f(a[1]));
    rr.z = f2b(silu_f(a[2])); rr.w = f2b(silu_f(a[3]));
    *(ushort4*)&xcb[t * DI + e4] = rr;
}

// ---------------------------------------------------------------------------
// Chunked selective scan (per-b). CHUNK=128, 96 chunks, dt_proj fused.
// ---------------------------------------------------------------------------
__global__ __launch_bounds__(256) void scan_pass1_k(
    const ushort* __restrict__ xcb, const float* __restrict__ dbc,
    const float* __restrict__ dtw_all, const float* __restrict__ dtb_all,
    const float* __restrict__ alog_all,
    float* __restrict__ PA, float* __restrict__ HB, int layer)
{
    const int bid = blockIdx.x;            // NCHK*2
    const int half = bid & 1;
    const int ci = bid >> 1;
    const int e = half * 256 + threadIdx.x;
    float w[DST], A[DST];
    const float* dtw = dtw_all + layer * (DI * DST) + e * DST;
    const float* al  = alog_all + layer * (DI * DST) + e * DST;
#pragma unroll
    for (int r = 0; r < DST; ++r) w[r] = dtw[r];
#pragma unroll
    for (int n = 0; n < DST; ++n) A[n] = -expf(al[n]) * 1.4426950408889634f;
    const float dtb = dtb_all[layer * DI + e];
    __shared__ __align__(16) float dl[LCHK][48];
    const int row0 = ci * LCHK;
    for (int i = threadIdx.x; i < LCHK * 48; i += 256)
        ((float*)dl)[i] = dbc[row0 * 48 + i];
    __syncthreads();
    float h[DST], pa[DST];
#pragma unroll
    for (int n = 0; n < DST; ++n) { h[n] = 0.f; pa[n] = 1.f; }
    for (int t = 0; t < LCHK; ++t) {
        float dtr = dtb;
#pragma unroll
        for (int r = 0; r < DST; ++r) dtr = fmaf(dl[t][r], w[r], dtr);
        const float dt = softplus_f(dtr);
        const float x = b2f(xcb[(row0 + t) * DI + e]);
        const float dx = dt * x;
#pragma unroll
        for (int n = 0; n < DST; ++n) {
            const float E = exp2f(dt * A[n]);
            h[n] = fmaf(h[n], E, dx * dl[t][16 + n]);
            pa[n] *= E;
        }
    }
    const int off = (ci * DI + e) * DST;
#pragma unroll
    for (int n = 0; n < DST; ++n) { PA[off + n] = pa[n]; HB[off + n] = h[n]; }
}

__global__ __launch_bounds__(256) void scan_pass2_k(
    const float* __restrict__ PA, float* __restrict__ HB)
{
    const int idx = blockIdx.x * 256 + threadIdx.x;   // < 8192
    float h = 0.f;
    for (int ci = 0; ci < NCHK; ++ci) {
        const int off = ci * 8192 + idx;
        const float pa = PA[off];
        const float hb = HB[off];
        const float nh = fmaf(h, pa, hb);
        HB[off] = h;          // exclusive chunk-input state
        h = nh;
    }
}

__global__ __launch_bounds__(256) void scan_pass3_k(
    const ushort* __restrict__ xcb, const float* __restrict__ dbc,
    const float* __restrict__ dtw_all, const float* __restrict__ dtb_all,
    const float* __restrict__ alog_all, const float* __restrict__ dsk_all,
    const float* __restrict__ HB, const float* __restrict__ Z,
    ushort* __restrict__ Yb, int layer)
{
    const int bid = blockIdx.x;
    const int half = bid & 1;
    const int ci = bid >> 1;
    const int e = half * 256 + threadIdx.x;
    float w[DST], A[DST];
    const float* dtw = dtw_all + layer * (DI * DST) + e * DST;
    const float* al  = alog_all + layer * (DI * DST) + e * DST;
#pragma unroll
    for (int r = 0; r < DST; ++r) w[r] = dtw[r];
#pragma unroll
    for (int n = 0; n < DST; ++n) A[n] = -expf(al[n]) * 1.4426950408889634f;
    const float dtb = dtb_all[layer * DI + e];
    const float dsk = dsk_all[layer * DI + e];
    __shared__ __align__(16) float dl[LCHK][48];
    const int row0 = ci * LCHK;
    for (int i = threadIdx.x; i < LCHK * 48; i += 256)
        ((float*)dl)[i] = dbc[row0 * 48 + i];
    __syncthreads();
    const int off = (ci * DI + e) * DST;
    float h[DST];
#pragma unroll
    for (int n = 0; n < DST; ++n) h[n] = HB[off + n];
    for (int t = 0; t < LCHK; ++t) {
        float dtr = dtb;
#pragma unroll
        for (int r = 0; r < DST; ++r) dtr = fmaf(dl[t][r], w[r], dtr);
        const float dt = softplus_f(dtr);
        const float x = b2f(xcb[(row0 + t) * DI + e]);
        const float dx = dt * x;
        float y = 0.f;
#pragma unroll
        for (int n = 0; n < DST; ++n) {
            const float E = exp2f(dt * A[n]);
            h[n] = fmaf(h[n], E, dx * dl[t][16 + n]);
            y = fmaf(h[n], dl[t][32 + n], y);
        }
        y = fmaf(x, dsk, y);
        const float z = Z[(row0 + t) * DI + e];
        Yb[(row0 + t) * DI + e] = f2b(y * silu_f(z));
    }
}

// ---------------------------------------------------------------------------
// Launch
// ---------------------------------------------------------------------------
extern "C" void kernel_launch(void* const* d_in, const int* in_sizes, int n_in,
                              void* d_out, int out_size, void* d_ws, size_t ws_size,
                              hipStream_t stream) {
    (void)in_sizes; (void)n_in; (void)out_size; (void)ws_size;
    const float* feat     = (const float*)d_in[0];
    const int*   nidx     = (const int*)d_in[1];
    const int*   order    = (const int*)d_in[2];
    const int*   inv      = (const int*)d_in[3];
    const float* conv_w   = (const float*)d_in[5];
    const float* conv_b   = (const float*)d_in[6];
    const float* cpe_fc_w = (const float*)d_in[7];
    const float* cpe_fc_b = (const float*)d_in[8];
    const float* cpe_ln_s = (const float*)d_in[9];
    const float* cpe_ln_b = (const float*)d_in[10];
    const float* in_proj_w = (const float*)d_in[11];
    const float* conv1d_w  = (const float*)d_in[12];
    const float* conv1d_b  = (const float*)d_in[13];
    const float* x_proj_w  = (const float*)d_in[14];
    const float* dt_proj_w = (const float*)d_in[15];
    const float* dt_proj_b = (const float*)d_in[16];
    const float* A_log     = (const float*)d_in[17];
    const float* D_skip    = (const float*)d_in[18];
    const float* out_proj_w = (const float*)d_in[19];
    const float* blk_ln_s  = (const float*)d_in[20];
    const float* blk_ln_b  = (const float*)d_in[21];
    const float* normf_s   = (const float*)d_in[22];
    const float* normf_b   = (const float*)d_in[23];
    const float* fuse_w1   = (const float*)d_in[24];
    const float* fuse_b1   = (const float*)d_in[25];
    const float* fuse_ln_s = (const float*)d_in[26];
    const float* fuse_ln_b = (const float*)d_in[27];
    const float* fuse_w2   = (const float*)d_in[28];
    const float* fuse_b2   = (const float*)d_in[29];
    float* out = (float*)d_out;
    float* ws = (float*)d_ws;

    // ---- workspace (38,690,816 floats = 147.6 MiB) ----
    float*  RES   = ws;                         // 12,582,912
    float*  ARENA = RES + 12582912;             // 18,874,368
    float*  DBC   = ARENA + 18874368;           //    589,824
    float*  PAb   = DBC + 589824;               //    786,432
    float*  HBb   = PAb + 786432;               //    786,432
    ushort* FEATB = (ushort*)(HBb + 786432);    //  4,194,304 us
    ushort* W2    = FEATB + 4194304;            //  1,769,472 us
    ushort* INWB  = W2 + 1769472;               //    524,288 us
    ushort* OUTWB = INWB + 524288;              //    262,144 us
    ushort* FW1B  = OUTWB + 262144;             //    196,608 us
    ushort* XPWB  = FW1B + 196608;              //     49,152 us
    ushort* HSLB  = XPWB + 49152;               //  3,145,728 us

    // arena views
    float*  X1  = ARENA;                        // CPE: 16384x256
    float*  X2  = ARENA + 4194304;
    float*  X3  = ARENA + 8388608;
    float*  XH  = ARENA;                        // mamba: 12288x512
    float*  Zb  = ARENA + 6291456;
    ushort* XCB = (ushort*)(ARENA + 12582912);  // 12288x512 bf16
    ushort* YB  = XCB + 6291456;                // 12288x512 bf16
    float*  H3  = ARENA;                        // final: 16384x768
    ushort* H3B = (ushort*)(ARENA + 12582912);  // 16384x768 bf16
    float*  F1  = ARENA;                        // fuse: 16384x256 (H3 dead)
    float*  F2  = ARENA + 4194304;

    const int BIG = 1 << 30;

    // ---- weight / input conversions ----
    f2b_k<<<2048, 256, 0, stream>>>(feat, FEATB, NPTS * DM);
    f2b_k<<<1024, 256, 0, stream>>>(in_proj_w, INWB, 2 * 1024 * DM);
    f2b_k<<<512, 256, 0, stream>>>(out_proj_w, OUTWB, 2 * DM * DI);
    f2b_k<<<512, 256, 0, stream>>>(fuse_w1, FW1B, DM * 768);
    f2b_k<<<128, 256, 0, stream>>>(x_proj_w, XPWB, 2 * 48 * DI);
    transpose_convw_k<<<dim3(KNB * DM / 32, DM / 32), 256, 0, stream>>>(conv_w, W2);

    // ---- CPE ----
    gather_bf<<<dim3(NPTS / 64, DM / 64), 256, 0, stream>>>(FEATB, nidx, W2, conv_b, X1);
    gemm_tn<<<dim3(NPTS / 64, DM / 64), 256, 0, stream>>>(X1, DM, cpe_fc_w, DM, cpe_fc_b,
                                                          X2, DM, DM, DM);
    ln_k<<<NPTS / 4, 256, 0, stream>>>(X2, feat, X3, cpe_ln_s, cpe_ln_b, 0, 0);
    serialize_k<<<SEQ / 4, 256, 0, stream>>>(X3, inv, RES);

    // ---- Mamba blocks (per layer, per batch element) ----
    for (int l = 0; l < 2; ++l) {
        for (int b = 0; b < BB; ++b) {
            float* RESb = RES + (size_t)b * LSEQ * DM;
            ln_k<<<LSEQ / 4, 256, 0, stream>>>(RESb, nullptr, HSLB,
                                               blk_ln_s + l * DM, blk_ln_b + l * DM, 0, 1);
            gemm_bf<<<dim3(LSEQ / 64, 16), 256, 0, stream>>>(
                HSLB, DM, INWB + l * 262144, DM, nullptr,
                XH, DI, Zb, DI, DI, 1024, DM, 0);
            conv1d_silu_k<<<LSEQ * 128 / 256, 256, 0, stream>>>(XH, conv1d_w + l * 2048,
                                                                conv1d_b + l * DI, XCB);
            gemm_bf<<<dim3(LSEQ / 64, 1), 256, 0, stream>>>(
                XCB, DI, XPWB + l * 24576, DI, nullptr,
                DBC, 48, nullptr, 0, BIG, 48, DI, 0);
            scan_pass1_k<<<NCHK * 2, 256, 0, stream>>>(XCB, DBC, dt_proj_w, dt_proj_b, A_log,
                                                       PAb, HBb, l);
            scan_pass2_k<<<32, 256, 0, stream>>>(PAb, HBb);
            scan_pass3_k<<<NCHK * 2, 256, 0, stream>>>(XCB, DBC, dt_proj_w, dt_proj_b, A_log,
                                                       D_skip, HBb, Zb, YB, l);
            gemm_bf<<<dim3(LSEQ / 64, 4), 256, 0, stream>>>(
                YB, DI, OUTWB + l * 131072, DI, nullptr,
                RESb, DM, nullptr, 0, BIG, DM, DI, 1);
        }
    }

    // ---- Final: deserialize -> rowwise LN -> fuse MLP ----
    deserialize_k<<<SEQ / 4, 256, 0, stream>>>(RES, order, H3);
    ln_k<<<SEQ / 4, 256, 0, stream>>>(H3, nullptr, H3B, normf_s, normf_b, 0, 1);
    gemm_bf<<<dim3(NPTS / 64, 4), 256, 0, stream>>>(
        H3B, 768, FW1B, 768, fuse_b1, F1, DM, nullptr, 0, BIG, DM, 768, 0);
    ln_k<<<NPTS / 4, 256, 0, stream>>>(F1, nullptr, F2, fuse_ln_s, fuse_ln_b, 1, 0);
    gemm_tn<<<dim3(NPTS / 64, DM / 64), 256, 0, stream>>>(F2, DM, fuse_w2, DM, fuse_b2,
                                                          out, DM, DM, DM);
}

// Round 4
// 1767.501 us; speedup vs baseline: 3.6193x; 1.9147x over previous
//
#include <hip/hip_runtime.h>
#include <hip/hip_bf16.h>

// ---------------------------------------------------------------------------
// Point-cloud Mamba pipeline v4: all GEMMs bf16 MFMA; full-SEQ scan (4x
// parallelism vs v3), in-place Z->Y gating, prefetched scan loads.
// Workspace: 50,126,848 floats = 191.2 MiB.
// ---------------------------------------------------------------------------

#define NPTS  16384
#define DM    256
#define KNB   27
#define BB    4
#define GG    4096
#define LSEQ  12288
#define SEQ   49152
#define DI    512
#define DST   16
#define NCHK  96
#define LCHK  128

typedef unsigned short ushort;
typedef __attribute__((ext_vector_type(8))) short short8;
typedef __attribute__((ext_vector_type(4))) float f32x4;

__device__ __forceinline__ float silu_f(float v) { return v / (1.f + __expf(-v)); }
__device__ __forceinline__ float softplus_f(float v) {
    return fmaxf(v, 0.f) + log1pf(expf(-fabsf(v)));
}
__device__ __forceinline__ float gelu_f(float v) {
    return 0.5f * v * (1.f + erff(v * 0.70710678118654752f));
}
__device__ __forceinline__ ushort f2b(float f) {
    __hip_bfloat16 h = __float2bfloat16(f);
    return __builtin_bit_cast(ushort, h);
}
__device__ __forceinline__ float b2f(ushort u) {
    unsigned int x = ((unsigned int)u) << 16;
    return __builtin_bit_cast(float, x);
}

// ---------------------------------------------------------------------------
// f32 -> bf16 convert (grid-stride)
// ---------------------------------------------------------------------------
__global__ __launch_bounds__(256) void f2b_k(const float* __restrict__ in,
                                             ushort* __restrict__ out, int n)
{
    for (int i = blockIdx.x * 256 + threadIdx.x; i < n; i += gridDim.x * 256)
        out[i] = f2b(in[i]);
}

// conv_w [27*256][256] -> W2 bf16 [256][6912] (transpose + convert)
__global__ __launch_bounds__(256) void transpose_convw_k(
    const float* __restrict__ cw, ushort* __restrict__ w2)
{
    __shared__ float T[32][33];
    const int kc0 = blockIdx.x * 32, d0 = blockIdx.y * 32;
    const int j = threadIdx.x & 31, r0 = (threadIdx.x >> 5) * 4;
#pragma unroll
    for (int r = 0; r < 4; ++r)
        T[r0 + r][j] = cw[(kc0 + r0 + r) * 256 + d0 + j];
    __syncthreads();
    const int i2 = threadIdx.x & 31;
#pragma unroll
    for (int r = 0; r < 4; ++r)
        w2[(d0 + r0 + r) * (KNB * DM) + kc0 + i2] = f2b(T[i2][r0 + r]);
}

// ---------------------------------------------------------------------------
// bf16 MFMA GEMM: C[m,j] = sum_c A[m,c]*W[j,c] (+bias). 64x64 tile, BK=64.
// omode: 0 = f32 split out1/out2; 1 = f32 accumulate out1; 2 = bf16 split.
// ---------------------------------------------------------------------------
__global__ __launch_bounds__(256) void gemm_bf(
    const ushort* __restrict__ A, int lda,
    const ushort* __restrict__ W, int ldw,
    const float* __restrict__ bias,
    void* __restrict__ out1, int ld1,
    void* __restrict__ out2, int ld2, int split,
    int N, int K, int omode)
{
    __shared__ __align__(16) ushort As[64 * 64];
    __shared__ __align__(16) ushort Bs[64 * 64];
    const int tid = threadIdx.x;
    const int w = tid >> 6, lane = tid & 63;
    const int m0 = blockIdx.x * 64, n0 = blockIdx.y * 64;
    f32x4 acc[4];
#pragma unroll
    for (int i = 0; i < 4; ++i) acc[i] = (f32x4){0.f, 0.f, 0.f, 0.f};

    for (int k0 = 0; k0 < K; k0 += 64) {
#pragma unroll
        for (int rr = 0; rr < 2; ++rr) {
            const int g = rr * 256 + tid;
            const int row = g >> 3, c8 = g & 7;
            const int phys = row * 64 + ((c8 ^ (row & 7)) << 3);
            *(short8*)&As[phys] = *(const short8*)&A[(size_t)(m0 + row) * lda + k0 + c8 * 8];
            short8 bv = (short8){0,0,0,0,0,0,0,0};
            if (n0 + row < N) bv = *(const short8*)&W[(size_t)(n0 + row) * ldw + k0 + c8 * 8];
            *(short8*)&Bs[phys] = bv;
        }
        __syncthreads();
#pragma unroll
        for (int kk = 0; kk < 2; ++kk) {
            const int row_a = w * 16 + (lane & 15);
            const int c8a = kk * 4 + (lane >> 4);
            const short8 av = *(const short8*)&As[row_a * 64 + ((c8a ^ (row_a & 7)) << 3)];
#pragma unroll
            for (int cf = 0; cf < 4; ++cf) {
                const int row_b = cf * 16 + (lane & 15);
                const short8 bv = *(const short8*)&Bs[row_b * 64 + ((c8a ^ (row_b & 7)) << 3)];
                acc[cf] = __builtin_amdgcn_mfma_f32_16x16x32_bf16(av, bv, acc[cf], 0, 0, 0);
            }
        }
        __syncthreads();
    }
    const int rbase = m0 + w * 16 + ((lane >> 4) << 2);
#pragma unroll
    for (int cf = 0; cf < 4; ++cf) {
        const int col = n0 + cf * 16 + (lane & 15);
        if (col < N) {
            const float bb = bias ? bias[col] : 0.f;
#pragma unroll
            for (int r = 0; r < 4; ++r) {
                const float v = acc[cf][r] + bb;
                const size_t row = rbase + r;
                if (omode == 1) {
                    ((float*)out1)[row * ld1 + col] += v;
                } else if (omode == 2) {
                    if (col < split) ((ushort*)out1)[row * ld1 + col] = f2b(v);
                    else             ((ushort*)out2)[row * ld2 + (col - split)] = f2b(v);
                } else {
                    if (col < split) ((float*)out1)[row * ld1 + col] = v;
                    else             ((float*)out2)[row * ld2 + (col - split)] = v;
                }
            }
        }
    }
}

// ---------------------------------------------------------------------------
// Gathered-A bf16 GEMM (gather-conv), bf16 output:
// X1[n,d] = sum_{k,c} featb[nidx[n,k],c] * W2[d, k*256+c] + conv_b[d]
// ---------------------------------------------------------------------------
__global__ __launch_bounds__(256) void gather_bf(
    const ushort* __restrict__ featb, const int* __restrict__ nidx,
    const ushort* __restrict__ w2, const float* __restrict__ bias,
    ushort* __restrict__ out)
{
    __shared__ __align__(16) ushort As[64 * 64];
    __shared__ __align__(16) ushort Bs[64 * 64];
    __shared__ int idxs[64 * 28];
    const int tid = threadIdx.x;
    const int w = tid >> 6, lane = tid & 63;
    const int m0 = blockIdx.x * 64, n0 = blockIdx.y * 64;
    for (int i = tid; i < 64 * KNB; i += 256) {
        const int row = i / KNB, kk = i - row * KNB;
        idxs[row * 28 + kk] = nidx[(m0 + row) * KNB + kk];
    }
    __syncthreads();
    f32x4 acc[4];
#pragma unroll
    for (int i = 0; i < 4; ++i) acc[i] = (f32x4){0.f, 0.f, 0.f, 0.f};

    for (int k0 = 0; k0 < KNB * DM; k0 += 64) {
        const int kt = k0 >> 8, c0 = k0 & 255;
#pragma unroll
        for (int rr = 0; rr < 2; ++rr) {
            const int g = rr * 256 + tid;
            const int row = g >> 3, c8 = g & 7;
            const int phys = row * 64 + ((c8 ^ (row & 7)) << 3);
            const int src = idxs[row * 28 + kt];
            *(short8*)&As[phys] = *(const short8*)&featb[src * DM + c0 + c8 * 8];
            *(short8*)&Bs[phys] = *(const short8*)&w2[(n0 + row) * (KNB * DM) + k0 + c8 * 8];
        }
        __syncthreads();
#pragma unroll
        for (int kk = 0; kk < 2; ++kk) {
            const int row_a = w * 16 + (lane & 15);
            const int c8a = kk * 4 + (lane >> 4);
            const short8 av = *(const short8*)&As[row_a * 64 + ((c8a ^ (row_a & 7)) << 3)];
#pragma unroll
            for (int cf = 0; cf < 4; ++cf) {
                const int row_b = cf * 16 + (lane & 15);
                const short8 bv = *(const short8*)&Bs[row_b * 64 + ((c8a ^ (row_b & 7)) << 3)];
                acc[cf] = __builtin_amdgcn_mfma_f32_16x16x32_bf16(av, bv, acc[cf], 0, 0, 0);
            }
        }
        __syncthreads();
    }
    const int rbase = m0 + w * 16 + ((lane >> 4) << 2);
#pragma unroll
    for (int cf = 0; cf < 4; ++cf) {
        const int col = n0 + cf * 16 + (lane & 15);
        const float bb = bias[col];
#pragma unroll
        for (int r = 0; r < 4; ++r)
            out[(rbase + r) * DM + col] = f2b(acc[cf][r] + bb);
    }
}

// ---------------------------------------------------------------------------
// LayerNorm over 256 cols (+optional residual add, +gelu, f32/bf16 out)
// ---------------------------------------------------------------------------
__global__ __launch_bounds__(256) void ln_k(
    const float* __restrict__ in, const float* __restrict__ add,
    void* __restrict__ outp,
    const float* __restrict__ s, const float* __restrict__ b,
    int do_gelu, int obf)
{
    const int wid = threadIdx.x >> 6, lane = threadIdx.x & 63;
    const size_t row = blockIdx.x * 4 + wid;
    const size_t base = row * DM + lane * 4;
    const float4 x4 = *(const float4*)&in[base];
    float sum = x4.x + x4.y + x4.z + x4.w;
#pragma unroll
    for (int off = 32; off > 0; off >>= 1) sum += __shfl_xor(sum, off, 64);
    const float mean = sum * 0.00390625f;
    const float d0 = x4.x - mean, d1 = x4.y - mean, d2 = x4.z - mean, d3 = x4.w - mean;
    float vs = d0 * d0 + d1 * d1 + d2 * d2 + d3 * d3;
#pragma unroll
    for (int off = 32; off > 0; off >>= 1) vs += __shfl_xor(vs, off, 64);
    const float rstd = rsqrtf(vs * 0.00390625f + 1e-5f);
    const float4 s4 = *(const float4*)&s[lane * 4];
    const float4 b4 = *(const float4*)&b[lane * 4];
    float o0 = d0 * rstd * s4.x + b4.x;
    float o1 = d1 * rstd * s4.y + b4.y;
    float o2 = d2 * rstd * s4.z + b4.z;
    float o3 = d3 * rstd * s4.w + b4.w;
    if (add) {
        const float4 a4 = *(const float4*)&add[base];
        o0 += a4.x; o1 += a4.y; o2 += a4.z; o3 += a4.w;
    }
    if (do_gelu) { o0 = gelu_f(o0); o1 = gelu_f(o1); o2 = gelu_f(o2); o3 = gelu_f(o3); }
    if (obf) {
        ushort4 r; r.x = f2b(o0); r.y = f2b(o1); r.z = f2b(o2); r.w = f2b(o3);
        *(ushort4*)&((ushort*)outp)[base] = r;
    } else {
        float4 r; r.x = o0; r.y = o1; r.z = o2; r.w = o3;
        *(float4*)&((float*)outp)[base] = r;
    }
}

// ---------------------------------------------------------------------------
// Serialize: RES[b*L + o*G + g, :] = X3[inverse[o, b*G+g], :]
// ---------------------------------------------------------------------------
__global__ __launch_bounds__(256) void serialize_k(
    const float* __restrict__ x3, const int* __restrict__ inv,
    float* __restrict__ res)
{
    const int wid = threadIdx.x >> 6, lane = threadIdx.x & 63;
    const int r = blockIdx.x * 4 + wid;
    const int b = r / LSEQ, l = r % LSEQ;
    const int o = l >> 12, g = l & 4095;
    const int src = inv[o * NPTS + b * GG + g];
    *(float4*)&res[(size_t)r * DM + lane * 4] = *(const float4*)&x3[(size_t)src * DM + lane * 4];
}

// Deserialize+regroup: H3[n, o*256+d] = RES[(m>>12)*L + o*G + (m&4095), d]
__global__ __launch_bounds__(256) void deserialize_k(
    const float* __restrict__ res, const int* __restrict__ order,
    float* __restrict__ h3)
{
    const int wid = threadIdx.x >> 6, lane = threadIdx.x & 63;
    const int p = blockIdx.x * 4 + wid;       // 0..49151
    const int o = p >> 14, n = p & 16383;
    const int m = order[o * NPTS + n];
    const int bp = m >> 12, gp = m & 4095;
    const size_t srow = (size_t)bp * LSEQ + o * GG + gp;
    *(float4*)&h3[(size_t)n * 768 + o * DM + lane * 4] = *(const float4*)&res[srow * DM + lane * 4];
}

// ---------------------------------------------------------------------------
// Depthwise causal conv1d (4 taps) + bias + silu. bf16 in, bf16 out. Per-b.
// ---------------------------------------------------------------------------
__global__ __launch_bounds__(256) void conv1d_silu_k(
    const ushort* __restrict__ xh, const float* __restrict__ cw,
    const float* __restrict__ cb, ushort* __restrict__ xcb)
{
    const int gidx = blockIdx.x * 256 + threadIdx.x;     // LSEQ*128
    const int t = gidx >> 7;
    const int e4 = (gidx & 127) << 2;
    float wta[4][4];
#pragma unroll
    for (int ee = 0; ee < 4; ++ee) {
        const float4 wv = *(const float4*)&cw[(e4 + ee) * 4];
        wta[ee][0] = wv.x; wta[ee][1] = wv.y; wta[ee][2] = wv.z; wta[ee][3] = wv.w;
    }
    const float4 c4 = *(const float4*)&cb[e4];
    float a[4] = {c4.x, c4.y, c4.z, c4.w};
#pragma unroll
    for (int j = 0; j < 4; ++j) {
        const int tt = t - 3 + j;
        if (tt >= 0) {
            const ushort4 x4 = *(const ushort4*)&xh[(size_t)tt * DI + e4];
            a[0] = fmaf(b2f(x4.x), wta[0][j], a[0]);
            a[1] = fmaf(b2f(x4.y), wta[1][j], a[1]);
            a[2] = fmaf(b2f(x4.z), wta[2][j], a[2]);
            a[3] = fmaf(b2f(x4.w), wta[3][j], a[3]);
        }
    }
    ushort4 rr;
    rr.x = f2b(silu_f(a[0])); rr.y = f2b(silu_f(a[1]));
    rr.z = f2b(silu_f(a[2])); rr.w = f2b(silu_f(a[3]));
    *(ushort4*)&xcb[(size_t)t * DI + e4] = rr;
}

// ---------------------------------------------------------------------------
// Chunked selective scan, all batches. grid (NCHK*2, BB). dt_proj fused.
// ---------------------------------------------------------------------------
__global__ __launch_bounds__(256) void scan_pass1_k(
    const ushort* __restrict__ xcb, const float* __restrict__ dbc,
    const float* __restrict__ dtw_all, const float* __restrict__ dtb_all,
    const float* __restrict__ alog_all,
    float* __restrict__ PA, float* __restrict__ HB, int layer)
{
    const int b = blockIdx.y;
    const int ci = blockIdx.x >> 1;
    const int half = blockIdx.x & 1;
    const int e = half * 256 + threadIdx.x;
    float w[DST], A[DST];
    const float* dtw = dtw_all + layer * (DI * DST) + e * DST;
    const float* al  = alog_all + layer * (DI * DST) + e * DST;
#pragma unroll
    for (int r = 0; r < DST; ++r) w[r] = dtw[r];
#pragma unroll
    for (int n = 0; n < DST; ++n) A[n] = -expf(al[n]) * 1.4426950408889634f;
    const float dtb = dtb_all[layer * DI + e];
    __shared__ __align__(16) float dl[LCHK][48];
    const int row0 = b * LSEQ + ci * LCHK;
    for (int i = threadIdx.x; i < LCHK * 48; i += 256)
        ((float*)dl)[i] = dbc[(size_t)row0 * 48 + i];
    __syncthreads();
    float h[DST], pa[DST];
#pragma unroll
    for (int n = 0; n < DST; ++n) { h[n] = 0.f; pa[n] = 1.f; }
    float xc = b2f(xcb[(size_t)row0 * DI + e]);
    for (int t = 0; t < LCHK; ++t) {
        float xn = 0.f;
        if (t + 1 < LCHK) xn = b2f(xcb[(size_t)(row0 + t + 1) * DI + e]);
        const float4* dlt = (const float4*)&dl[t][0];
        float dtr = dtb;
#pragma unroll
        for (int q = 0; q < 4; ++q) {
            const float4 dq = dlt[q];
            dtr = fmaf(dq.w, w[4*q+3], fmaf(dq.z, w[4*q+2],
                  fmaf(dq.y, w[4*q+1], fmaf(dq.x, w[4*q+0], dtr))));
        }
        const float dt = softplus_f(dtr);
        const float dx = dt * xc;
#pragma unroll
        for (int q = 0; q < 4; ++q) {
            const float4 bq = dlt[4+q];
            const float bb[4] = {bq.x, bq.y, bq.z, bq.w};
#pragma unroll
            for (int j = 0; j < 4; ++j) {
                const int n = 4*q + j;
                const float E = exp2f(dt * A[n]);
                h[n] = fmaf(h[n], E, dx * bb[j]);
                pa[n] *= E;
            }
        }
        xc = xn;
    }
    const size_t off = ((size_t)(b * NCHK + ci) * DI + e) * DST;
#pragma unroll
    for (int n = 0; n < DST; ++n) { PA[off + n] = pa[n]; HB[off + n] = h[n]; }
}

__global__ __launch_bounds__(256) void scan_pass2_k(
    const float* __restrict__ PA, float* __restrict__ HB)
{
    const int idx = blockIdx.x * 256 + threadIdx.x;   // < 4*8192
    const int b = idx >> 13, rem = idx & 8191;
    float h = 0.f;
    for (int ci = 0; ci < NCHK; ++ci) {
        const size_t off = ((size_t)(b * NCHK + ci) << 13) + rem;
        const float pa = PA[off];
        const float hb = HB[off];
        const float nh = fmaf(h, pa, hb);
        HB[off] = h;          // exclusive chunk-input state
        h = nh;
    }
}

__global__ __launch_bounds__(256) void scan_pass3_k(
    const ushort* __restrict__ xcb, const float* __restrict__ dbc,
    const float* __restrict__ dtw_all, const float* __restrict__ dtb_all,
    const float* __restrict__ alog_all, const float* __restrict__ dsk_all,
    const float* __restrict__ HB, ushort* zy, int layer)
{
    const int b = blockIdx.y;
    const int ci = blockIdx.x >> 1;
    const int half = blockIdx.x & 1;
    const int e = half * 256 + threadIdx.x;
    float w[DST], A[DST];
    const float* dtw = dtw_all + layer * (DI * DST) + e * DST;
    const float* al  = alog_all + layer * (DI * DST) + e * DST;
#pragma unroll
    for (int r = 0; r < DST; ++r) w[r] = dtw[r];
#pragma unroll
    for (int n = 0; n < DST; ++n) A[n] = -expf(al[n]) * 1.4426950408889634f;
    const float dtb = dtb_all[layer * DI + e];
    const float dsk = dsk_all[layer * DI + e];
    __shared__ __align__(16) float dl[LCHK][48];
    const int row0 = b * LSEQ + ci * LCHK;
    for (int i = threadIdx.x; i < LCHK * 48; i += 256)
        ((float*)dl)[i] = dbc[(size_t)row0 * 48 + i];
    __syncthreads();
    const size_t off = ((size_t)(b * NCHK + ci) * DI + e) * DST;
    float h[DST];
#pragma unroll
    for (int n = 0; n < DST; ++n) h[n] = HB[off + n];
    float xc = b2f(xcb[(size_t)row0 * DI + e]);
    float zc = b2f(zy[(size_t)row0 * DI + e]);
    for (int t = 0; t < LCHK; ++t) {
        float xn = 0.f, zn = 0.f;
        if (t + 1 < LCHK) {
            xn = b2f(xcb[(size_t)(row0 + t + 1) * DI + e]);
            zn = b2f(zy[(size_t)(row0 + t + 1) * DI + e]);
        }
        const float4* dlt = (const float4*)&dl[t][0];
        float dtr = dtb;
#pragma unroll
        for (int q = 0; q < 4; ++q) {
            const float4 dq = dlt[q];
            dtr = fmaf(dq.w, w[4*q+3], fmaf(dq.z, w[4*q+2],
                  fmaf(dq.y, w[4*q+1], fmaf(dq.x, w[4*q+0], dtr))));
        }
        const float dt = softplus_f(dtr);
        const float dx = dt * xc;
        float y = 0.f;
#pragma unroll
        for (int q = 0; q < 4; ++q) {
            const float4 bq = dlt[4+q];
            const float4 cq = dlt[8+q];
            const float bb[4] = {bq.x, bq.y, bq.z, bq.w};
            const float cc[4] = {cq.x, cq.y, cq.z, cq.w};
#pragma unroll
            for (int j = 0; j < 4; ++j) {
                const int n = 4*q + j;
                const float E = exp2f(dt * A[n]);
                h[n] = fmaf(h[n], E, dx * bb[j]);
                y = fmaf(h[n], cc[j], y);
            }
        }
        y = fmaf(xc, dsk, y);
        zy[(size_t)(row0 + t) * DI + e] = f2b(y * silu_f(zc));
        xc = xn; zc = zn;
    }
}

// ---------------------------------------------------------------------------
// Launch
// ---------------------------------------------------------------------------
extern "C" void kernel_launch(void* const* d_in, const int* in_sizes, int n_in,
                              void* d_out, int out_size, void* d_ws, size_t ws_size,
                              hipStream_t stream) {
    (void)in_sizes; (void)n_in; (void)out_size; (void)ws_size;
    const float* feat     = (const float*)d_in[0];
    const int*   nidx     = (const int*)d_in[1];
    const int*   order    = (const int*)d_in[2];
    const int*   inv      = (const int*)d_in[3];
    const float* conv_w   = (const float*)d_in[5];
    const float* conv_b   = (const float*)d_in[6];
    const float* cpe_fc_w = (const float*)d_in[7];
    const float* cpe_fc_b = (const float*)d_in[8];
    const float* cpe_ln_s = (const float*)d_in[9];
    const float* cpe_ln_b = (const float*)d_in[10];
    const float* in_proj_w = (const float*)d_in[11];
    const float* conv1d_w  = (const float*)d_in[12];
    const float* conv1d_b  = (const float*)d_in[13];
    const float* x_proj_w  = (const float*)d_in[14];
    const float* dt_proj_w = (const float*)d_in[15];
    const float* dt_proj_b = (const float*)d_in[16];
    const float* A_log     = (const float*)d_in[17];
    const float* D_skip    = (const float*)d_in[18];
    const float* out_proj_w = (const float*)d_in[19];
    const float* blk_ln_s  = (const float*)d_in[20];
    const float* blk_ln_b  = (const float*)d_in[21];
    const float* normf_s   = (const float*)d_in[22];
    const float* normf_b   = (const float*)d_in[23];
    const float* fuse_w1   = (const float*)d_in[24];
    const float* fuse_b1   = (const float*)d_in[25];
    const float* fuse_ln_s = (const float*)d_in[26];
    const float* fuse_ln_b = (const float*)d_in[27];
    const float* fuse_w2   = (const float*)d_in[28];
    const float* fuse_b2   = (const float*)d_in[29];
    float* out = (float*)d_out;
    float* ws = (float*)d_ws;

    // ---- workspace regions (f32 words); total 50,126,848 = 191.2 MiB ----
    float* RES   = ws;                          // 12,582,912
    float* ZY    = RES + 12582912;              // 12,582,912
    float* XCBR  = ZY + 12582912;               // 12,582,912
    float* XHB_f = XCBR + 12582912;             //  3,145,728
    float* DBC   = XHB_f + 3145728;             //  2,359,296
    float* PA    = DBC + 2359296;               //  3,145,728
    float* HB    = PA + 3145728;                //  3,145,728
    float* SW    = HB + 3145728;                //    581,632

    ushort* ZY_us = (ushort*)ZY;
    ushort* XCB   = (ushort*)XCBR;              // SEQ*512 bf16
    ushort* HSLB  = XCB + 12582912;             // SEQ*256 bf16 (tail overlap)
    ushort* FEATB = XCB;                        // CPE-only (dies at layer0 conv1d)
    ushort* W2    = XCB + 4194304;              // CPE-only
    ushort* XHB   = (ushort*)XHB_f;             // per-b 12288*512 bf16
    ushort* SWu   = (ushort*)SW;
    ushort* INWB  = SWu;                        // 524,288
    ushort* OUTWB = INWB + 524288;              // 262,144
    ushort* FW1B  = OUTWB + 262144;             // 196,608
    ushort* XPWB  = FW1B + 196608;              //  49,152
    ushort* CPEWB = XPWB + 49152;               //  65,536
    ushort* FW2B  = CPEWB + 65536;              //  65,536

    // CPE views (inside ZY, unused until mamba)
    ushort* X1B = ZY_us;                        // 16384x256 bf16
    float*  X2  = ZY + 2097152;
    float*  X3  = ZY + 6291456;
    // fuse views
    float*  H3  = ZY;                           // 16384x768 f32
    ushort* H3B = XCB;                          // 16384x768 bf16
    float*  F1  = XCBR + 6291456;               // 16384x256 f32
    ushort* F2B = (ushort*)(XCBR + 10485760);   // 16384x256 bf16

    const int BIG = 1 << 30;

    // ---- conversions ----
    f2b_k<<<2048, 256, 0, stream>>>(feat, FEATB, NPTS * DM);
    f2b_k<<<1024, 256, 0, stream>>>(in_proj_w, INWB, 2 * 1024 * DM);
    f2b_k<<<512, 256, 0, stream>>>(out_proj_w, OUTWB, 2 * DM * DI);
    f2b_k<<<512, 256, 0, stream>>>(fuse_w1, FW1B, DM * 768);
    f2b_k<<<128, 256, 0, stream>>>(x_proj_w, XPWB, 2 * 48 * DI);
    f2b_k<<<256, 256, 0, stream>>>(cpe_fc_w, CPEWB, DM * DM);
    f2b_k<<<256, 256, 0, stream>>>(fuse_w2, FW2B, DM * DM);
    transpose_convw_k<<<dim3(KNB * DM / 32, DM / 32), 256, 0, stream>>>(conv_w, W2);

    // ---- CPE ----
    gather_bf<<<dim3(NPTS / 64, DM / 64), 256, 0, stream>>>(FEATB, nidx, W2, conv_b, X1B);
    gemm_bf<<<dim3(NPTS / 64, 4), 256, 0, stream>>>(X1B, DM, CPEWB, DM, cpe_fc_b,
                                                    X2, DM, nullptr, 0, BIG, DM, DM, 0);
    ln_k<<<NPTS / 4, 256, 0, stream>>>(X2, feat, X3, cpe_ln_s, cpe_ln_b, 0, 0);
    serialize_k<<<SEQ / 4, 256, 0, stream>>>(X3, inv, RES);

    // ---- Mamba blocks ----
    for (int l = 0; l < 2; ++l) {
        ln_k<<<SEQ / 4, 256, 0, stream>>>(RES, nullptr, HSLB,
                                          blk_ln_s + l * DM, blk_ln_b + l * DM, 0, 1);
        for (int b = 0; b < BB; ++b) {
            gemm_bf<<<dim3(LSEQ / 64, 16), 256, 0, stream>>>(
                HSLB + (size_t)b * LSEQ * DM, DM, INWB + l * 262144, DM, nullptr,
                XHB, DI, ZY_us + (size_t)b * LSEQ * DI, DI, DI, 1024, DM, 2);
            conv1d_silu_k<<<LSEQ * 128 / 256, 256, 0, stream>>>(
                XHB, conv1d_w + l * 2048, conv1d_b + l * DI,
                XCB + (size_t)b * LSEQ * DI);
        }
        gemm_bf<<<dim3(SEQ / 64, 1), 256, 0, stream>>>(
            XCB, DI, XPWB + l * 24576, DI, nullptr,
            DBC, 48, nullptr, 0, BIG, 48, DI, 0);
        scan_pass1_k<<<dim3(NCHK * 2, BB), 256, 0, stream>>>(
            XCB, DBC, dt_proj_w, dt_proj_b, A_log, PA, HB, l);
        scan_pass2_k<<<128, 256, 0, stream>>>(PA, HB);
        scan_pass3_k<<<dim3(NCHK * 2, BB), 256, 0, stream>>>(
            XCB, DBC, dt_proj_w, dt_proj_b, A_log, D_skip, HB, ZY_us, l);
        gemm_bf<<<dim3(SEQ / 64, 4), 256, 0, stream>>>(
            ZY_us, DI, OUTWB + l * 131072, DI, nullptr,
            RES, DM, nullptr, 0, BIG, DM, DI, 1);
    }

    // ---- Final: deserialize -> rowwise LN -> fuse MLP ----
    deserialize_k<<<SEQ / 4, 256, 0, stream>>>(RES, order, H3);
    ln_k<<<SEQ / 4, 256, 0, stream>>>(H3, nullptr, H3B, normf_s, normf_b, 0, 1);
    gemm_bf<<<dim3(NPTS / 64, 4), 256, 0, stream>>>(
        H3B, 768, FW1B, 768, fuse_b1, F1, DM, nullptr, 0, BIG, DM, 768, 0);
    ln_k<<<NPTS / 4, 256, 0, stream>>>(F1, nullptr, F2B, fuse_ln_s, fuse_ln_b, 1, 1);
    gemm_bf<<<dim3(NPTS / 64, 4), 256, 0, stream>>>(
        F2B, DM, FW2B, DM, fuse_b2, out, DM, nullptr, 0, BIG, DM, DM, 0);
}

// Round 5
// 1310.677 us; speedup vs baseline: 4.8808x; 1.3485x over previous
//
#include <hip/hip_runtime.h>
#include <hip/hip_bf16.h>

// ---------------------------------------------------------------------------
// Point-cloud Mamba pipeline v5:
//  - scan: structured-A fast path (1 exp2 + power table instead of 16 exps),
//    cheap softplus, ILP dt-dot, scalar pa1. Generic fallback kept.
//  - GEMMs: global_load_lds(16B) staging; 128^2 tile for in/out_proj,
//    64^2 glld tile for gather/cpe/fuse; x_proj keeps reg-staged path.
// Workspace layout identical to v4 (191.2 MiB, known good).
// ---------------------------------------------------------------------------

#define NPTS  16384
#define DM    256
#define KNB   27
#define BB    4
#define GG    4096
#define LSEQ  12288
#define SEQ   49152
#define DI    512
#define DST   16
#define NCHK  96
#define LCHK  128
#define LOG2E 1.4426950408889634f

typedef unsigned short ushort;
typedef __attribute__((ext_vector_type(8))) short short8;
typedef __attribute__((ext_vector_type(4))) float f32x4;

__device__ __forceinline__ float silu_f(float v) { return v / (1.f + __expf(-v)); }
__device__ __forceinline__ float softplus_fast(float v) {
    return fmaxf(v, 0.f) + __logf(1.f + __expf(-fabsf(v)));
}
__device__ __forceinline__ float gelu_f(float v) {
    return 0.5f * v * (1.f + erff(v * 0.70710678118654752f));
}
__device__ __forceinline__ ushort f2b(float f) {
    __hip_bfloat16 h = __float2bfloat16(f);
    return __builtin_bit_cast(ushort, h);
}
__device__ __forceinline__ float b2f(ushort u) {
    unsigned int x = ((unsigned int)u) << 16;
    return __builtin_bit_cast(float, x);
}
__device__ __forceinline__ void gl2lds16(const ushort* g, ushort* l) {
    __builtin_amdgcn_global_load_lds(
        (const __attribute__((address_space(1))) void*)g,
        (__attribute__((address_space(3))) void*)l, 16, 0, 0);
}

// ---------------------------------------------------------------------------
__global__ __launch_bounds__(256) void f2b_k(const float* __restrict__ in,
                                             ushort* __restrict__ out, int n)
{
    for (int i = blockIdx.x * 256 + threadIdx.x; i < n; i += gridDim.x * 256)
        out[i] = f2b(in[i]);
}

// conv_w [27*256][256] -> W2 bf16 [256][6912]
__global__ __launch_bounds__(256) void transpose_convw_k(
    const float* __restrict__ cw, ushort* __restrict__ w2)
{
    __shared__ float T[32][33];
    const int kc0 = blockIdx.x * 32, d0 = blockIdx.y * 32;
    const int j = threadIdx.x & 31, r0 = (threadIdx.x >> 5) * 4;
#pragma unroll
    for (int r = 0; r < 4; ++r)
        T[r0 + r][j] = cw[(kc0 + r0 + r) * 256 + d0 + j];
    __syncthreads();
    const int i2 = threadIdx.x & 31;
#pragma unroll
    for (int r = 0; r < 4; ++r)
        w2[(d0 + r0 + r) * (KNB * DM) + kc0 + i2] = f2b(T[i2][r0 + r]);
}

// ---------------------------------------------------------------------------
// 128x128 bf16 MFMA GEMM, BK=64, glld staging, 4 waves (2x2 of 64x64).
// omode: 1 = f32 accumulate out1; 2 = bf16 split out1/out2 at `split`.
// M%128==0, N%128==0, K%64==0.
// ---------------------------------------------------------------------------
__global__ __launch_bounds__(256) void gemm_bf128(
    const ushort* __restrict__ A, int lda,
    const ushort* __restrict__ W, int ldw,
    void* __restrict__ out1, int ld1,
    void* __restrict__ out2, int ld2, int split,
    int K, int omode)
{
    __shared__ __align__(16) ushort As[128 * 64];
    __shared__ __align__(16) ushort Bs[128 * 64];
    const int tid = threadIdx.x;
    const int w = tid >> 6, lane = tid & 63;
    const int wr = w >> 1, wc = w & 1;
    const int m0 = blockIdx.x * 128, n0 = blockIdx.y * 128;
    f32x4 acc[4][4];
#pragma unroll
    for (int i = 0; i < 4; ++i)
#pragma unroll
        for (int j = 0; j < 4; ++j) acc[i][j] = (f32x4){0.f, 0.f, 0.f, 0.f};

    for (int k0 = 0; k0 < K; k0 += 64) {
#pragma unroll
        for (int i = 0; i < 4; ++i) {
            const int rb = (i * 4 + w) * 8;
            const int row = rb + (lane >> 3);
            const int c8 = lane & 7;
            gl2lds16(&A[(size_t)(m0 + row) * lda + k0 + c8 * 8], &As[rb * 64]);
            gl2lds16(&W[(size_t)(n0 + row) * ldw + k0 + c8 * 8], &Bs[rb * 64]);
        }
        __syncthreads();
#pragma unroll
        for (int ks = 0; ks < 2; ++ks) {
            short8 a[4], b[4];
#pragma unroll
            for (int mi = 0; mi < 4; ++mi)
                a[mi] = *(const short8*)&As[(wr * 64 + mi * 16 + (lane & 15)) * 64 + ks * 32 + (lane >> 4) * 8];
#pragma unroll
            for (int ni = 0; ni < 4; ++ni)
                b[ni] = *(const short8*)&Bs[(wc * 64 + ni * 16 + (lane & 15)) * 64 + ks * 32 + (lane >> 4) * 8];
#pragma unroll
            for (int mi = 0; mi < 4; ++mi)
#pragma unroll
                for (int ni = 0; ni < 4; ++ni)
                    acc[mi][ni] = __builtin_amdgcn_mfma_f32_16x16x32_bf16(a[mi], b[ni], acc[mi][ni], 0, 0, 0);
        }
        __syncthreads();
    }
    const int rbase = m0 + wr * 64 + ((lane >> 4) << 2);
#pragma unroll
    for (int mi = 0; mi < 4; ++mi) {
#pragma unroll
        for (int ni = 0; ni < 4; ++ni) {
            const int col = n0 + wc * 64 + ni * 16 + (lane & 15);
#pragma unroll
            for (int r = 0; r < 4; ++r) {
                const size_t row = rbase + mi * 16 + r;
                const float v = acc[mi][ni][r];
                if (omode == 1) {
                    ((float*)out1)[row * ld1 + col] += v;
                } else {
                    if (col < split) ((ushort*)out1)[row * ld1 + col] = f2b(v);
                    else             ((ushort*)out2)[row * ld2 + (col - split)] = f2b(v);
                }
            }
        }
    }
}

// ---------------------------------------------------------------------------
// 64x64 bf16 MFMA GEMM, BK=64, glld staging, f32 out (+bias).
// M%64==0, N%64==0, K%64==0.
// ---------------------------------------------------------------------------
__global__ __launch_bounds__(256) void gemm_bf64g(
    const ushort* __restrict__ A, int lda,
    const ushort* __restrict__ W, int ldw,
    const float* __restrict__ bias,
    float* __restrict__ out, int ldo, int K)
{
    __shared__ __align__(16) ushort As[64 * 64];
    __shared__ __align__(16) ushort Bs[64 * 64];
    const int tid = threadIdx.x;
    const int w = tid >> 6, lane = tid & 63;
    const int m0 = blockIdx.x * 64, n0 = blockIdx.y * 64;
    f32x4 acc[4];
#pragma unroll
    for (int i = 0; i < 4; ++i) acc[i] = (f32x4){0.f, 0.f, 0.f, 0.f};

    for (int k0 = 0; k0 < K; k0 += 64) {
#pragma unroll
        for (int i = 0; i < 2; ++i) {
            const int rb = (i * 4 + w) * 8;
            const int row = rb + (lane >> 3);
            const int c8 = lane & 7;
            gl2lds16(&A[(size_t)(m0 + row) * lda + k0 + c8 * 8], &As[rb * 64]);
            gl2lds16(&W[(size_t)(n0 + row) * ldw + k0 + c8 * 8], &Bs[rb * 64]);
        }
        __syncthreads();
#pragma unroll
        for (int ks = 0; ks < 2; ++ks) {
            const short8 av = *(const short8*)&As[(w * 16 + (lane & 15)) * 64 + ks * 32 + (lane >> 4) * 8];
#pragma unroll
            for (int cf = 0; cf < 4; ++cf) {
                const short8 bv = *(const short8*)&Bs[(cf * 16 + (lane & 15)) * 64 + ks * 32 + (lane >> 4) * 8];
                acc[cf] = __builtin_amdgcn_mfma_f32_16x16x32_bf16(av, bv, acc[cf], 0, 0, 0);
            }
        }
        __syncthreads();
    }
    const int rbase = m0 + w * 16 + ((lane >> 4) << 2);
#pragma unroll
    for (int cf = 0; cf < 4; ++cf) {
        const int col = n0 + cf * 16 + (lane & 15);
        const float bb = bias ? bias[col] : 0.f;
#pragma unroll
        for (int r = 0; r < 4; ++r)
            out[(size_t)(rbase + r) * ldo + col] = acc[cf][r] + bb;
    }
}

// ---------------------------------------------------------------------------
// Gathered-A 64x64 GEMM (gather-conv), glld staging, bf16 out (+bias).
// ---------------------------------------------------------------------------
__global__ __launch_bounds__(256) void gather_bf(
    const ushort* __restrict__ featb, const int* __restrict__ nidx,
    const ushort* __restrict__ w2, const float* __restrict__ bias,
    ushort* __restrict__ out)
{
    __shared__ __align__(16) ushort As[64 * 64];
    __shared__ __align__(16) ushort Bs[64 * 64];
    const int tid = threadIdx.x;
    const int w = tid >> 6, lane = tid & 63;
    const int m0 = blockIdx.x * 64, n0 = blockIdx.y * 64;
    f32x4 acc[4];
#pragma unroll
    for (int i = 0; i < 4; ++i) acc[i] = (f32x4){0.f, 0.f, 0.f, 0.f};

    for (int k0 = 0; k0 < KNB * DM; k0 += 64) {
        const int kt = k0 >> 8, c0 = k0 & 255;
#pragma unroll
        for (int i = 0; i < 2; ++i) {
            const int rb = (i * 4 + w) * 8;
            const int row = rb + (lane >> 3);
            const int c8 = lane & 7;
            const int src = nidx[(m0 + row) * KNB + kt];
            gl2lds16(&featb[(size_t)src * DM + c0 + c8 * 8], &As[rb * 64]);
            gl2lds16(&w2[(size_t)(n0 + row) * (KNB * DM) + k0 + c8 * 8], &Bs[rb * 64]);
        }
        __syncthreads();
#pragma unroll
        for (int ks = 0; ks < 2; ++ks) {
            const short8 av = *(const short8*)&As[(w * 16 + (lane & 15)) * 64 + ks * 32 + (lane >> 4) * 8];
#pragma unroll
            for (int cf = 0; cf < 4; ++cf) {
                const short8 bv = *(const short8*)&Bs[(cf * 16 + (lane & 15)) * 64 + ks * 32 + (lane >> 4) * 8];
                acc[cf] = __builtin_amdgcn_mfma_f32_16x16x32_bf16(av, bv, acc[cf], 0, 0, 0);
            }
        }
        __syncthreads();
    }
    const int rbase = m0 + w * 16 + ((lane >> 4) << 2);
#pragma unroll
    for (int cf = 0; cf < 4; ++cf) {
        const int col = n0 + cf * 16 + (lane & 15);
        const float bb = bias[col];
#pragma unroll
        for (int r = 0; r < 4; ++r)
            out[(size_t)(rbase + r) * DM + col] = f2b(acc[cf][r] + bb);
    }
}

// ---------------------------------------------------------------------------
// 64x64 reg-staged GEMM (XOR swizzle) for N not multiple of 64 (x_proj N=48).
// f32 out.
// ---------------------------------------------------------------------------
__global__ __launch_bounds__(256) void gemm_bf64r(
    const ushort* __restrict__ A, int lda,
    const ushort* __restrict__ W, int ldw,
    float* __restrict__ out, int ldo, int N, int K)
{
    __shared__ __align__(16) ushort As[64 * 64];
    __shared__ __align__(16) ushort Bs[64 * 64];
    const int tid = threadIdx.x;
    const int w = tid >> 6, lane = tid & 63;
    const int m0 = blockIdx.x * 64, n0 = blockIdx.y * 64;
    f32x4 acc[4];
#pragma unroll
    for (int i = 0; i < 4; ++i) acc[i] = (f32x4){0.f, 0.f, 0.f, 0.f};

    for (int k0 = 0; k0 < K; k0 += 64) {
#pragma unroll
        for (int rr = 0; rr < 2; ++rr) {
            const int g = rr * 256 + tid;
            const int row = g >> 3, c8 = g & 7;
            const int phys = row * 64 + ((c8 ^ (row & 7)) << 3);
            *(short8*)&As[phys] = *(const short8*)&A[(size_t)(m0 + row) * lda + k0 + c8 * 8];
            short8 bv = (short8){0,0,0,0,0,0,0,0};
            if (n0 + row < N) bv = *(const short8*)&W[(size_t)(n0 + row) * ldw + k0 + c8 * 8];
            *(short8*)&Bs[phys] = bv;
        }
        __syncthreads();
#pragma unroll
        for (int kk = 0; kk < 2; ++kk) {
            const int row_a = w * 16 + (lane & 15);
            const int c8a = kk * 4 + (lane >> 4);
            const short8 av = *(const short8*)&As[row_a * 64 + ((c8a ^ (row_a & 7)) << 3)];
#pragma unroll
            for (int cf = 0; cf < 4; ++cf) {
                const int row_b = cf * 16 + (lane & 15);
                const short8 bv = *(const short8*)&Bs[row_b * 64 + ((c8a ^ (row_b & 7)) << 3)];
                acc[cf] = __builtin_amdgcn_mfma_f32_16x16x32_bf16(av, bv, acc[cf], 0, 0, 0);
            }
        }
        __syncthreads();
    }
    const int rbase = m0 + w * 16 + ((lane >> 4) << 2);
#pragma unroll
    for (int cf = 0; cf < 4; ++cf) {
        const int col = n0 + cf * 16 + (lane & 15);
        if (col < N) {
#pragma unroll
            for (int r = 0; r < 4; ++r)
                out[(size_t)(rbase + r) * ldo + col] = acc[cf][r];
        }
    }
}

// ---------------------------------------------------------------------------
// LayerNorm over 256 cols (+optional residual add, +gelu, f32/bf16 out)
// ---------------------------------------------------------------------------
__global__ __launch_bounds__(256) void ln_k(
    const float* __restrict__ in, const float* __restrict__ add,
    void* __restrict__ outp,
    const float* __restrict__ s, const float* __restrict__ b,
    int do_gelu, int obf)
{
    const int wid = threadIdx.x >> 6, lane = threadIdx.x & 63;
    const size_t row = blockIdx.x * 4 + wid;
    const size_t base = row * DM + lane * 4;
    const float4 x4 = *(const float4*)&in[base];
    float sum = x4.x + x4.y + x4.z + x4.w;
#pragma unroll
    for (int off = 32; off > 0; off >>= 1) sum += __shfl_xor(sum, off, 64);
    const float mean = sum * 0.00390625f;
    const float d0 = x4.x - mean, d1 = x4.y - mean, d2 = x4.z - mean, d3 = x4.w - mean;
    float vs = d0 * d0 + d1 * d1 + d2 * d2 + d3 * d3;
#pragma unroll
    for (int off = 32; off > 0; off >>= 1) vs += __shfl_xor(vs, off, 64);
    const float rstd = rsqrtf(vs * 0.00390625f + 1e-5f);
    const float4 s4 = *(const float4*)&s[lane * 4];
    const float4 b4 = *(const float4*)&b[lane * 4];
    float o0 = d0 * rstd * s4.x + b4.x;
    float o1 = d1 * rstd * s4.y + b4.y;
    float o2 = d2 * rstd * s4.z + b4.z;
    float o3 = d3 * rstd * s4.w + b4.w;
    if (add) {
        const float4 a4 = *(const float4*)&add[base];
        o0 += a4.x; o1 += a4.y; o2 += a4.z; o3 += a4.w;
    }
    if (do_gelu) { o0 = gelu_f(o0); o1 = gelu_f(o1); o2 = gelu_f(o2); o3 = gelu_f(o3); }
    if (obf) {
        ushort4 r; r.x = f2b(o0); r.y = f2b(o1); r.z = f2b(o2); r.w = f2b(o3);
        *(ushort4*)&((ushort*)outp)[base] = r;
    } else {
        float4 r; r.x = o0; r.y = o1; r.z = o2; r.w = o3;
        *(float4*)&((float*)outp)[base] = r;
    }
}

// ---------------------------------------------------------------------------
__global__ __launch_bounds__(256) void serialize_k(
    const float* __restrict__ x3, const int* __restrict__ inv,
    float* __restrict__ res)
{
    const int wid = threadIdx.x >> 6, lane = threadIdx.x & 63;
    const int r = blockIdx.x * 4 + wid;
    const int b = r / LSEQ, l = r % LSEQ;
    const int o = l >> 12, g = l & 4095;
    const int src = inv[o * NPTS + b * GG + g];
    *(float4*)&res[(size_t)r * DM + lane * 4] = *(const float4*)&x3[(size_t)src * DM + lane * 4];
}

__global__ __launch_bounds__(256) void deserialize_k(
    const float* __restrict__ res, const int* __restrict__ order,
    float* __restrict__ h3)
{
    const int wid = threadIdx.x >> 6, lane = threadIdx.x & 63;
    const int p = blockIdx.x * 4 + wid;
    const int o = p >> 14, n = p & 16383;
    const int m = order[o * NPTS + n];
    const int bp = m >> 12, gp = m & 4095;
    const size_t srow = (size_t)bp * LSEQ + o * GG + gp;
    *(float4*)&h3[(size_t)n * 768 + o * DM + lane * 4] = *(const float4*)&res[srow * DM + lane * 4];
}

// ---------------------------------------------------------------------------
__global__ __launch_bounds__(256) void conv1d_silu_k(
    const ushort* __restrict__ xh, const float* __restrict__ cw,
    const float* __restrict__ cb, ushort* __restrict__ xcb)
{
    const int gidx = blockIdx.x * 256 + threadIdx.x;
    const int t = gidx >> 7;
    const int e4 = (gidx & 127) << 2;
    float wta[4][4];
#pragma unroll
    for (int ee = 0; ee < 4; ++ee) {
        const float4 wv = *(const float4*)&cw[(e4 + ee) * 4];
        wta[ee][0] = wv.x; wta[ee][1] = wv.y; wta[ee][2] = wv.z; wta[ee][3] = wv.w;
    }
    const float4 c4 = *(const float4*)&cb[e4];
    float a[4] = {c4.x, c4.y, c4.z, c4.w};
#pragma unroll
    for (int j = 0; j < 4; ++j) {
        const int tt = t - 3 + j;
        if (tt >= 0) {
            const ushort4 x4 = *(const ushort4*)&xh[(size_t)tt * DI + e4];
            a[0] = fmaf(b2f(x4.x), wta[0][j], a[0]);
            a[1] = fmaf(b2f(x4.y), wta[1][j], a[1]);
            a[2] = fmaf(b2f(x4.z), wta[2][j], a[2]);
            a[3] = fmaf(b2f(x4.w), wta[3][j], a[3]);
        }
    }
    ushort4 rr;
    rr.x = f2b(silu_f(a[0])); rr.y = f2b(silu_f(a[1]));
    rr.z = f2b(silu_f(a[2])); rr.w = f2b(silu_f(a[3]));
    *(ushort4*)&xcb[(size_t)t * DI + e4] = rr;
}

// ---------------------------------------------------------------------------
// Chunked selective scan. Structured-A fast path: A[n] = (n+1)*A[0]
// (reference A_log = log(arange(1..16)) broadcast) -> decay factors are
// powers of one exp2. Generic fallback if structure check fails.
// ---------------------------------------------------------------------------
__device__ __forceinline__ float dt_dot(const float4* dlt, const float* w, float dtb)
{
    const float4 q0 = dlt[0], q1 = dlt[1], q2 = dlt[2], q3 = dlt[3];
    float s0 = fmaf(q0.x, w[0], dtb);
    float s1 = q0.y * w[1];
    float s2 = q0.z * w[2];
    float s3 = q0.w * w[3];
    s0 = fmaf(q1.x, w[4], s0); s1 = fmaf(q1.y, w[5], s1);
    s2 = fmaf(q1.z, w[6], s2); s3 = fmaf(q1.w, w[7], s3);
    s0 = fmaf(q2.x, w[8], s0); s1 = fmaf(q2.y, w[9], s1);
    s2 = fmaf(q2.z, w[10], s2); s3 = fmaf(q2.w, w[11], s3);
    s0 = fmaf(q3.x, w[12], s0); s1 = fmaf(q3.y, w[13], s1);
    s2 = fmaf(q3.z, w[14], s2); s3 = fmaf(q3.w, w[15], s3);
    return (s0 + s1) + (s2 + s3);
}

__device__ __forceinline__ void pow_table(float e1, float* E)
{
    const float e2 = e1 * e1, e4 = e2 * e2, e8 = e4 * e4;
    E[0] = e1;       E[1] = e2;       E[2] = e2 * e1;  E[3] = e4;
    E[4] = e4 * e1;  E[5] = e4 * e2;  E[6] = E[5] * e1; E[7] = e8;
    E[8] = e8 * e1;  E[9] = e8 * e2;  E[10] = E[9] * e1; E[11] = e8 * e4;
    E[12] = E[11] * e1; E[13] = E[11] * e2; E[14] = E[13] * e1; E[15] = e8 * e8;
}

__global__ __launch_bounds__(256) void scan_pass1_k(
    const ushort* __restrict__ xcb, const float* __restrict__ dbc,
    const float* __restrict__ dtw_all, const float* __restrict__ dtb_all,
    const float* __restrict__ alog_all,
    float* __restrict__ PA, float* __restrict__ HB, int layer)
{
    const int b = blockIdx.y;
    const int ci = blockIdx.x >> 1;
    const int half = blockIdx.x & 1;
    const int e = half * 256 + threadIdx.x;
    float w[DST], A[DST];
    const float* dtw = dtw_all + layer * (DI * DST) + e * DST;
    const float* al  = alog_all + layer * (DI * DST) + e * DST;
#pragma unroll
    for (int r = 0; r < DST; ++r) w[r] = dtw[r];
#pragma unroll
    for (int n = 0; n < DST; ++n) A[n] = -__expf(al[n]);
    bool structA = true;
#pragma unroll
    for (int n = 1; n < DST; ++n)
        structA = structA && (fabsf(A[n] - (n + 1) * A[0]) <= 1e-4f * (n + 1));
    const float lA = A[0] * LOG2E;
    const float dtb = dtb_all[layer * DI + e];
    __shared__ __align__(16) float dl[LCHK][48];
    const int row0 = b * LSEQ + ci * LCHK;
    for (int i = threadIdx.x; i < LCHK * 48; i += 256)
        ((float*)dl)[i] = dbc[(size_t)row0 * 48 + i];
    __syncthreads();
    float h[DST];
#pragma unroll
    for (int n = 0; n < DST; ++n) h[n] = 0.f;
    const size_t off = ((size_t)(b * NCHK + ci) * DI + e) * DST;

    if (structA) {
        float pa1 = 1.f;
        float xc = b2f(xcb[(size_t)row0 * DI + e]);
        for (int t = 0; t < LCHK; ++t) {
            float xn = 0.f;
            if (t + 1 < LCHK) xn = b2f(xcb[(size_t)(row0 + t + 1) * DI + e]);
            const float4* dlt = (const float4*)&dl[t][0];
            const float dt = softplus_fast(dt_dot(dlt, w, dtb));
            const float e1 = exp2f(dt * lA);
            float E[DST];
            pow_table(e1, E);
            const float dx = dt * xc;
            pa1 *= e1;
#pragma unroll
            for (int q = 0; q < 4; ++q) {
                const float4 bq = dlt[4 + q];
                h[4*q+0] = fmaf(h[4*q+0], E[4*q+0], dx * bq.x);
                h[4*q+1] = fmaf(h[4*q+1], E[4*q+1], dx * bq.y);
                h[4*q+2] = fmaf(h[4*q+2], E[4*q+2], dx * bq.z);
                h[4*q+3] = fmaf(h[4*q+3], E[4*q+3], dx * bq.w);
            }
            xc = xn;
        }
        float P[DST];
        pow_table(pa1, P);
#pragma unroll
        for (int n = 0; n < DST; ++n) { PA[off + n] = P[n]; HB[off + n] = h[n]; }
    } else {
        float Alog2[DST], pa[DST];
#pragma unroll
        for (int n = 0; n < DST; ++n) { Alog2[n] = A[n] * LOG2E; pa[n] = 1.f; }
        float xc = b2f(xcb[(size_t)row0 * DI + e]);
        for (int t = 0; t < LCHK; ++t) {
            float xn = 0.f;
            if (t + 1 < LCHK) xn = b2f(xcb[(size_t)(row0 + t + 1) * DI + e]);
            const float4* dlt = (const float4*)&dl[t][0];
            const float dt = softplus_fast(dt_dot(dlt, w, dtb));
            const float dx = dt * xc;
#pragma unroll
            for (int q = 0; q < 4; ++q) {
                const float4 bq = dlt[4 + q];
                const float bb[4] = {bq.x, bq.y, bq.z, bq.w};
#pragma unroll
                for (int j = 0; j < 4; ++j) {
                    const int n = 4*q + j;
                    const float E = exp2f(dt * Alog2[n]);
                    h[n] = fmaf(h[n], E, dx * bb[j]);
                    pa[n] *= E;
                }
            }
            xc = xn;
        }
#pragma unroll
        for (int n = 0; n < DST; ++n) { PA[off + n] = pa[n]; HB[off + n] = h[n]; }
    }
}

__global__ __launch_bounds__(256) void scan_pass2_k(
    const float* __restrict__ PA, float* __restrict__ HB)
{
    const int idx = blockIdx.x * 256 + threadIdx.x;
    const int b = idx >> 13, rem = idx & 8191;
    float h = 0.f;
    for (int ci = 0; ci < NCHK; ++ci) {
        const size_t off = ((size_t)(b * NCHK + ci) << 13) + rem;
        const float pa = PA[off];
        const float hb = HB[off];
        const float nh = fmaf(h, pa, hb);
        HB[off] = h;
        h = nh;
    }
}

__global__ __launch_bounds__(256) void scan_pass3_k(
    const ushort* __restrict__ xcb, const float* __restrict__ dbc,
    const float* __restrict__ dtw_all, const float* __restrict__ dtb_all,
    const float* __restrict__ alog_all, const float* __restrict__ dsk_all,
    const float* __restrict__ HB, ushort* zy, int layer)
{
    const int b = blockIdx.y;
    const int ci = blockIdx.x >> 1;
    const int half = blockIdx.x & 1;
    const int e = half * 256 + threadIdx.x;
    float w[DST], A[DST];
    const float* dtw = dtw_all + layer * (DI * DST) + e * DST;
    const float* al  = alog_all + layer * (DI * DST) + e * DST;
#pragma unroll
    for (int r = 0; r < DST; ++r) w[r] = dtw[r];
#pragma unroll
    for (int n = 0; n < DST; ++n) A[n] = -__expf(al[n]);
    bool structA = true;
#pragma unroll
    for (int n = 1; n < DST; ++n)
        structA = structA && (fabsf(A[n] - (n + 1) * A[0]) <= 1e-4f * (n + 1));
    const float lA = A[0] * LOG2E;
    const float dtb = dtb_all[layer * DI + e];
    const float dsk = dsk_all[layer * DI + e];
    __shared__ __align__(16) float dl[LCHK][48];
    const int row0 = b * LSEQ + ci * LCHK;
    for (int i = threadIdx.x; i < LCHK * 48; i += 256)
        ((float*)dl)[i] = dbc[(size_t)row0 * 48 + i];
    __syncthreads();
    const size_t off = ((size_t)(b * NCHK + ci) * DI + e) * DST;
    float h[DST];
#pragma unroll
    for (int n = 0; n < DST; ++n) h[n] = HB[off + n];
    float xc = b2f(xcb[(size_t)row0 * DI + e]);
    float zc = b2f(zy[(size_t)row0 * DI + e]);

    if (structA) {
        for (int t = 0; t < LCHK; ++t) {
            float xn = 0.f, zn = 0.f;
            if (t + 1 < LCHK) {
                xn = b2f(xcb[(size_t)(row0 + t + 1) * DI + e]);
                zn = b2f(zy[(size_t)(row0 + t + 1) * DI + e]);
            }
            const float4* dlt = (const float4*)&dl[t][0];
            const float dt = softplus_fast(dt_dot(dlt, w, dtb));
            const float e1 = exp2f(dt * lA);
            float E[DST];
            pow_table(e1, E);
            const float dx = dt * xc;
            float y0 = 0.f, y1 = 0.f, y2 = 0.f, y3 = 0.f;
#pragma unroll
            for (int q = 0; q < 4; ++q) {
                const float4 bq = dlt[4 + q];
                const float4 cq = dlt[8 + q];
                h[4*q+0] = fmaf(h[4*q+0], E[4*q+0], dx * bq.x);
                h[4*q+1] = fmaf(h[4*q+1], E[4*q+1], dx * bq.y);
                h[4*q+2] = fmaf(h[4*q+2], E[4*q+2], dx * bq.z);
                h[4*q+3] = fmaf(h[4*q+3], E[4*q+3], dx * bq.w);
                y0 = fmaf(h[4*q+0], cq.x, y0);
                y1 = fmaf(h[4*q+1], cq.y, y1);
                y2 = fmaf(h[4*q+2], cq.z, y2);
                y3 = fmaf(h[4*q+3], cq.w, y3);
            }
            float y = (y0 + y1) + (y2 + y3);
            y = fmaf(xc, dsk, y);
            zy[(size_t)(row0 + t) * DI + e] = f2b(y * silu_f(zc));
            xc = xn; zc = zn;
        }
    } else {
        float Alog2[DST];
#pragma unroll
        for (int n = 0; n < DST; ++n) Alog2[n] = A[n] * LOG2E;
        for (int t = 0; t < LCHK; ++t) {
            float xn = 0.f, zn = 0.f;
            if (t + 1 < LCHK) {
                xn = b2f(xcb[(size_t)(row0 + t + 1) * DI + e]);
                zn = b2f(zy[(size_t)(row0 + t + 1) * DI + e]);
            }
            const float4* dlt = (const float4*)&dl[t][0];
            const float dt = softplus_fast(dt_dot(dlt, w, dtb));
            const float dx = dt * xc;
            float y = 0.f;
#pragma unroll
            for (int q = 0; q < 4; ++q) {
                const float4 bq = dlt[4 + q];
                const float4 cq = dlt[8 + q];
                const float bb[4] = {bq.x, bq.y, bq.z, bq.w};
                const float cc[4] = {cq.x, cq.y, cq.z, cq.w};
#pragma unroll
                for (int j = 0; j < 4; ++j) {
                    const int n = 4*q + j;
                    const float E = exp2f(dt * Alog2[n]);
                    h[n] = fmaf(h[n], E, dx * bb[j]);
                    y = fmaf(h[n], cc[j], y);
                }
            }
            y = fmaf(xc, dsk, y);
            zy[(size_t)(row0 + t) * DI + e] = f2b(y * silu_f(zc));
            xc = xn; zc = zn;
        }
    }
}

// ---------------------------------------------------------------------------
// Launch
// ---------------------------------------------------------------------------
extern "C" void kernel_launch(void* const* d_in, const int* in_sizes, int n_in,
                              void* d_out, int out_size, void* d_ws, size_t ws_size,
                              hipStream_t stream) {
    (void)in_sizes; (void)n_in; (void)out_size; (void)ws_size;
    const float* feat     = (const float*)d_in[0];
    const int*   nidx     = (const int*)d_in[1];
    const int*   order    = (const int*)d_in[2];
    const int*   inv      = (const int*)d_in[3];
    const float* conv_w   = (const float*)d_in[5];
    const float* conv_b   = (const float*)d_in[6];
    const float* cpe_fc_w = (const float*)d_in[7];
    const float* cpe_fc_b = (const float*)d_in[8];
    const float* cpe_ln_s = (const float*)d_in[9];
    const float* cpe_ln_b = (const float*)d_in[10];
    const float* in_proj_w = (const float*)d_in[11];
    const float* conv1d_w  = (const float*)d_in[12];
    const float* conv1d_b  = (const float*)d_in[13];
    const float* x_proj_w  = (const float*)d_in[14];
    const float* dt_proj_w = (const float*)d_in[15];
    const float* dt_proj_b = (const float*)d_in[16];
    const float* A_log     = (const float*)d_in[17];
    const float* D_skip    = (const float*)d_in[18];
    const float* out_proj_w = (const float*)d_in[19];
    const float* blk_ln_s  = (const float*)d_in[20];
    const float* blk_ln_b  = (const float*)d_in[21];
    const float* normf_s   = (const float*)d_in[22];
    const float* normf_b   = (const float*)d_in[23];
    const float* fuse_w1   = (const float*)d_in[24];
    const float* fuse_b1   = (const float*)d_in[25];
    const float* fuse_ln_s = (const float*)d_in[26];
    const float* fuse_ln_b = (const float*)d_in[27];
    const float* fuse_w2   = (const float*)d_in[28];
    const float* fuse_b2   = (const float*)d_in[29];
    float* out = (float*)d_out;
    float* ws = (float*)d_ws;

    // ---- workspace (identical layout to v4; 191.2 MiB) ----
    float* RES   = ws;                          // 12,582,912
    float* ZY    = RES + 12582912;              // 12,582,912
    float* XCBR  = ZY + 12582912;               // 12,582,912
    float* XHB_f = XCBR + 12582912;             //  3,145,728
    float* DBC   = XHB_f + 3145728;             //  2,359,296
    float* PA    = DBC + 2359296;               //  3,145,728
    float* HB    = PA + 3145728;                //  3,145,728
    float* SW    = HB + 3145728;                //    581,632

    ushort* ZY_us = (ushort*)ZY;
    ushort* XCB   = (ushort*)XCBR;
    ushort* HSLB  = XCB + 12582912;
    ushort* FEATB = XCB;
    ushort* W2    = XCB + 4194304;
    ushort* XHB   = (ushort*)XHB_f;
    ushort* SWu   = (ushort*)SW;
    ushort* INWB  = SWu;
    ushort* OUTWB = INWB + 524288;
    ushort* FW1B  = OUTWB + 262144;
    ushort* XPWB  = FW1B + 196608;
    ushort* CPEWB = XPWB + 49152;
    ushort* FW2B  = CPEWB + 65536;

    ushort* X1B = ZY_us;
    float*  X2  = ZY + 2097152;
    float*  X3  = ZY + 6291456;
    float*  H3  = ZY;
    ushort* H3B = XCB;
    float*  F1  = XCBR + 6291456;
    ushort* F2B = (ushort*)(XCBR + 10485760);

    // ---- conversions ----
    f2b_k<<<2048, 256, 0, stream>>>(feat, FEATB, NPTS * DM);
    f2b_k<<<1024, 256, 0, stream>>>(in_proj_w, INWB, 2 * 1024 * DM);
    f2b_k<<<512, 256, 0, stream>>>(out_proj_w, OUTWB, 2 * DM * DI);
    f2b_k<<<512, 256, 0, stream>>>(fuse_w1, FW1B, DM * 768);
    f2b_k<<<128, 256, 0, stream>>>(x_proj_w, XPWB, 2 * 48 * DI);
    f2b_k<<<256, 256, 0, stream>>>(cpe_fc_w, CPEWB, DM * DM);
    f2b_k<<<256, 256, 0, stream>>>(fuse_w2, FW2B, DM * DM);
    transpose_convw_k<<<dim3(KNB * DM / 32, DM / 32), 256, 0, stream>>>(conv_w, W2);

    // ---- CPE ----
    gather_bf<<<dim3(NPTS / 64, DM / 64), 256, 0, stream>>>(FEATB, nidx, W2, conv_b, X1B);
    gemm_bf64g<<<dim3(NPTS / 64, DM / 64), 256, 0, stream>>>(X1B, DM, CPEWB, DM, cpe_fc_b,
                                                             X2, DM, DM);
    ln_k<<<NPTS / 4, 256, 0, stream>>>(X2, feat, X3, cpe_ln_s, cpe_ln_b, 0, 0);
    serialize_k<<<SEQ / 4, 256, 0, stream>>>(X3, inv, RES);

    // ---- Mamba blocks ----
    for (int l = 0; l < 2; ++l) {
        ln_k<<<SEQ / 4, 256, 0, stream>>>(RES, nullptr, HSLB,
                                          blk_ln_s + l * DM, blk_ln_b + l * DM, 0, 1);
        for (int b = 0; b < BB; ++b) {
            gemm_bf128<<<dim3(LSEQ / 128, 8), 256, 0, stream>>>(
                HSLB + (size_t)b * LSEQ * DM, DM, INWB + l * 262144, DM,
                XHB, DI, ZY_us + (size_t)b * LSEQ * DI, DI, 512, DM, 2);
            conv1d_silu_k<<<LSEQ * 128 / 256, 256, 0, stream>>>(
                XHB, conv1d_w + l * 2048, conv1d_b + l * DI,
                XCB + (size_t)b * LSEQ * DI);
        }
        gemm_bf64r<<<dim3(SEQ / 64, 1), 256, 0, stream>>>(
            XCB, DI, XPWB + l * 24576, DI, DBC, 48, 48, DI);
        scan_pass1_k<<<dim3(NCHK * 2, BB), 256, 0, stream>>>(
            XCB, DBC, dt_proj_w, dt_proj_b, A_log, PA, HB, l);
        scan_pass2_k<<<128, 256, 0, stream>>>(PA, HB);
        scan_pass3_k<<<dim3(NCHK * 2, BB), 256, 0, stream>>>(
            XCB, DBC, dt_proj_w, dt_proj_b, A_log, D_skip, HB, ZY_us, l);
        gemm_bf128<<<dim3(SEQ / 128, 2), 256, 0, stream>>>(
            ZY_us, DI, OUTWB + l * 131072, DI,
            RES, DM, nullptr, 0, 1 << 30, DI, 1);
    }

    // ---- Final: deserialize -> rowwise LN -> fuse MLP ----
    deserialize_k<<<SEQ / 4, 256, 0, stream>>>(RES, order, H3);
    ln_k<<<SEQ / 4, 256, 0, stream>>>(H3, nullptr, H3B, normf_s, normf_b, 0, 1);
    gemm_bf64g<<<dim3(NPTS / 64, DM / 64), 256, 0, stream>>>(H3B, 768, FW1B, 768, fuse_b1,
                                                             F1, DM, 768);
    ln_k<<<NPTS / 4, 256, 0, stream>>>(F1, nullptr, F2B, fuse_ln_s, fuse_ln_b, 1, 1);
    gemm_bf64g<<<dim3(NPTS / 64, DM / 64), 256, 0, stream>>>(F2B, DM, FW2B, DM, fuse_b2,
                                                             out, DM, DM);
}

// Round 7
// 1179.696 us; speedup vs baseline: 5.4227x; 1.1110x over previous
//
#include <hip/hip_runtime.h>
#include <hip/hip_bf16.h>

// ---------------------------------------------------------------------------
// Point-cloud Mamba pipeline v6 (resubmit after infra failure):
//  v5 + bank-conflict fix for global_load_lds GEMMs (rule #21):
//  linear LDS dest + pre-swizzled per-lane GLOBAL source + XOR-swizzled read.
//  gather_bf keeps the idxs LDS stage (breaks nidx->glld serial dependency).
// Workspace layout identical to v4/v5 (191.2 MiB, known good).
// ---------------------------------------------------------------------------

#define NPTS  16384
#define DM    256
#define KNB   27
#define BB    4
#define GG    4096
#define LSEQ  12288
#define SEQ   49152
#define DI    512
#define DST   16
#define NCHK  96
#define LCHK  128
#define LOG2E 1.4426950408889634f

typedef unsigned short ushort;
typedef __attribute__((ext_vector_type(8))) short short8;
typedef __attribute__((ext_vector_type(4))) float f32x4;

__device__ __forceinline__ float silu_f(float v) { return v / (1.f + __expf(-v)); }
__device__ __forceinline__ float softplus_fast(float v) {
    return fmaxf(v, 0.f) + __logf(1.f + __expf(-fabsf(v)));
}
__device__ __forceinline__ float gelu_f(float v) {
    return 0.5f * v * (1.f + erff(v * 0.70710678118654752f));
}
__device__ __forceinline__ ushort f2b(float f) {
    __hip_bfloat16 h = __float2bfloat16(f);
    return __builtin_bit_cast(ushort, h);
}
__device__ __forceinline__ float b2f(ushort u) {
    unsigned int x = ((unsigned int)u) << 16;
    return __builtin_bit_cast(float, x);
}
__device__ __forceinline__ void gl2lds16(const ushort* g, ushort* l) {
    __builtin_amdgcn_global_load_lds(
        (const __attribute__((address_space(1))) void*)g,
        (__attribute__((address_space(3))) void*)l, 16, 0, 0);
}

// ---------------------------------------------------------------------------
__global__ __launch_bounds__(256) void f2b_k(const float* __restrict__ in,
                                             ushort* __restrict__ out, int n)
{
    for (int i = blockIdx.x * 256 + threadIdx.x; i < n; i += gridDim.x * 256)
        out[i] = f2b(in[i]);
}

// conv_w [27*256][256] -> W2 bf16 [256][6912]
__global__ __launch_bounds__(256) void transpose_convw_k(
    const float* __restrict__ cw, ushort* __restrict__ w2)
{
    __shared__ float T[32][33];
    const int kc0 = blockIdx.x * 32, d0 = blockIdx.y * 32;
    const int j = threadIdx.x & 31, r0 = (threadIdx.x >> 5) * 4;
#pragma unroll
    for (int r = 0; r < 4; ++r)
        T[r0 + r][j] = cw[(kc0 + r0 + r) * 256 + d0 + j];
    __syncthreads();
    const int i2 = threadIdx.x & 31;
#pragma unroll
    for (int r = 0; r < 4; ++r)
        w2[(d0 + r0 + r) * (KNB * DM) + kc0 + i2] = f2b(T[i2][r0 + r]);
}

// ---------------------------------------------------------------------------
// 128x128 bf16 MFMA GEMM, BK=64, glld staging with pre-swizzled source.
// omode: 1 = f32 accumulate out1; 2 = bf16 split out1/out2 at `split`.
// M%128==0, N%128==0, K%64==0.
// ---------------------------------------------------------------------------
__global__ __launch_bounds__(256) void gemm_bf128(
    const ushort* __restrict__ A, int lda,
    const ushort* __restrict__ W, int ldw,
    void* __restrict__ out1, int ld1,
    void* __restrict__ out2, int ld2, int split,
    int K, int omode)
{
    __shared__ __align__(16) ushort As[128 * 64];
    __shared__ __align__(16) ushort Bs[128 * 64];
    const int tid = threadIdx.x;
    const int w = tid >> 6, lane = tid & 63;
    const int wr = w >> 1, wc = w & 1;
    const int m0 = blockIdx.x * 128, n0 = blockIdx.y * 128;
    f32x4 acc[4][4];
#pragma unroll
    for (int i = 0; i < 4; ++i)
#pragma unroll
        for (int j = 0; j < 4; ++j) acc[i][j] = (f32x4){0.f, 0.f, 0.f, 0.f};

    for (int k0 = 0; k0 < K; k0 += 64) {
#pragma unroll
        for (int i = 0; i < 4; ++i) {
            const int rb = (i * 4 + w) * 8;
            const int row = rb + (lane >> 3);
            const int c8 = (lane & 7) ^ (row & 7);   // pre-swizzled source granule
            gl2lds16(&A[(size_t)(m0 + row) * lda + k0 + c8 * 8], &As[rb * 64]);
            gl2lds16(&W[(size_t)(n0 + row) * ldw + k0 + c8 * 8], &Bs[rb * 64]);
        }
        __syncthreads();
#pragma unroll
        for (int ks = 0; ks < 2; ++ks) {
            const int g = ks * 4 + (lane >> 4);      // logical granule
            short8 a[4], b[4];
#pragma unroll
            for (int mi = 0; mi < 4; ++mi) {
                const int ra = wr * 64 + mi * 16 + (lane & 15);
                a[mi] = *(const short8*)&As[ra * 64 + ((g ^ (ra & 7)) << 3)];
            }
#pragma unroll
            for (int ni = 0; ni < 4; ++ni) {
                const int rbw = wc * 64 + ni * 16 + (lane & 15);
                b[ni] = *(const short8*)&Bs[rbw * 64 + ((g ^ (rbw & 7)) << 3)];
            }
#pragma unroll
            for (int mi = 0; mi < 4; ++mi)
#pragma unroll
                for (int ni = 0; ni < 4; ++ni)
                    acc[mi][ni] = __builtin_amdgcn_mfma_f32_16x16x32_bf16(a[mi], b[ni], acc[mi][ni], 0, 0, 0);
        }
        __syncthreads();
    }
    const int rbase = m0 + wr * 64 + ((lane >> 4) << 2);
#pragma unroll
    for (int mi = 0; mi < 4; ++mi) {
#pragma unroll
        for (int ni = 0; ni < 4; ++ni) {
            const int col = n0 + wc * 64 + ni * 16 + (lane & 15);
#pragma unroll
            for (int r = 0; r < 4; ++r) {
                const size_t row = rbase + mi * 16 + r;
                const float v = acc[mi][ni][r];
                if (omode == 1) {
                    ((float*)out1)[row * ld1 + col] += v;
                } else {
                    if (col < split) ((ushort*)out1)[row * ld1 + col] = f2b(v);
                    else             ((ushort*)out2)[row * ld2 + (col - split)] = f2b(v);
                }
            }
        }
    }
}

// ---------------------------------------------------------------------------
// 64x64 bf16 MFMA GEMM, BK=64, glld staging (pre-swizzled), f32 out (+bias).
// M%64==0, N%64==0, K%64==0.
// ---------------------------------------------------------------------------
__global__ __launch_bounds__(256) void gemm_bf64g(
    const ushort* __restrict__ A, int lda,
    const ushort* __restrict__ W, int ldw,
    const float* __restrict__ bias,
    float* __restrict__ out, int ldo, int K)
{
    __shared__ __align__(16) ushort As[64 * 64];
    __shared__ __align__(16) ushort Bs[64 * 64];
    const int tid = threadIdx.x;
    const int w = tid >> 6, lane = tid & 63;
    const int m0 = blockIdx.x * 64, n0 = blockIdx.y * 64;
    f32x4 acc[4];
#pragma unroll
    for (int i = 0; i < 4; ++i) acc[i] = (f32x4){0.f, 0.f, 0.f, 0.f};

    for (int k0 = 0; k0 < K; k0 += 64) {
#pragma unroll
        for (int i = 0; i < 2; ++i) {
            const int rb = (i * 4 + w) * 8;
            const int row = rb + (lane >> 3);
            const int c8 = (lane & 7) ^ (row & 7);
            gl2lds16(&A[(size_t)(m0 + row) * lda + k0 + c8 * 8], &As[rb * 64]);
            gl2lds16(&W[(size_t)(n0 + row) * ldw + k0 + c8 * 8], &Bs[rb * 64]);
        }
        __syncthreads();
#pragma unroll
        for (int ks = 0; ks < 2; ++ks) {
            const int g = ks * 4 + (lane >> 4);
            const int ra = w * 16 + (lane & 15);
            const short8 av = *(const short8*)&As[ra * 64 + ((g ^ (ra & 7)) << 3)];
#pragma unroll
            for (int cf = 0; cf < 4; ++cf) {
                const int rbw = cf * 16 + (lane & 15);
                const short8 bv = *(const short8*)&Bs[rbw * 64 + ((g ^ (rbw & 7)) << 3)];
                acc[cf] = __builtin_amdgcn_mfma_f32_16x16x32_bf16(av, bv, acc[cf], 0, 0, 0);
            }
        }
        __syncthreads();
    }
    const int rbase = m0 + w * 16 + ((lane >> 4) << 2);
#pragma unroll
    for (int cf = 0; cf < 4; ++cf) {
        const int col = n0 + cf * 16 + (lane & 15);
        const float bb = bias ? bias[col] : 0.f;
#pragma unroll
        for (int r = 0; r < 4; ++r)
            out[(size_t)(rbase + r) * ldo + col] = acc[cf][r] + bb;
    }
}

// ---------------------------------------------------------------------------
// Gathered-A 64x64 GEMM (gather-conv), glld staging (pre-swizzled), bf16 out.
// ---------------------------------------------------------------------------
__global__ __launch_bounds__(256) void gather_bf(
    const ushort* __restrict__ featb, const int* __restrict__ nidx,
    const ushort* __restrict__ w2, const float* __restrict__ bias,
    ushort* __restrict__ out)
{
    __shared__ __align__(16) ushort As[64 * 64];
    __shared__ __align__(16) ushort Bs[64 * 64];
    __shared__ int idxs[64 * 28];
    const int tid = threadIdx.x;
    const int w = tid >> 6, lane = tid & 63;
    const int m0 = blockIdx.x * 64, n0 = blockIdx.y * 64;
    for (int i = tid; i < 64 * KNB; i += 256) {
        const int row = i / KNB, kk = i - row * KNB;
        idxs[row * 28 + kk] = nidx[(m0 + row) * KNB + kk];
    }
    __syncthreads();
    f32x4 acc[4];
#pragma unroll
    for (int i = 0; i < 4; ++i) acc[i] = (f32x4){0.f, 0.f, 0.f, 0.f};

    for (int k0 = 0; k0 < KNB * DM; k0 += 64) {
        const int kt = k0 >> 8, c0 = k0 & 255;
#pragma unroll
        for (int i = 0; i < 2; ++i) {
            const int rb = (i * 4 + w) * 8;
            const int row = rb + (lane >> 3);
            const int c8 = (lane & 7) ^ (row & 7);
            const int src = idxs[row * 28 + kt];
            gl2lds16(&featb[(size_t)src * DM + c0 + c8 * 8], &As[rb * 64]);
            gl2lds16(&w2[(size_t)(n0 + row) * (KNB * DM) + k0 + c8 * 8], &Bs[rb * 64]);
        }
        __syncthreads();
#pragma unroll
        for (int ks = 0; ks < 2; ++ks) {
            const int g = ks * 4 + (lane >> 4);
            const int ra = w * 16 + (lane & 15);
            const short8 av = *(const short8*)&As[ra * 64 + ((g ^ (ra & 7)) << 3)];
#pragma unroll
            for (int cf = 0; cf < 4; ++cf) {
                const int rbw = cf * 16 + (lane & 15);
                const short8 bv = *(const short8*)&Bs[rbw * 64 + ((g ^ (rbw & 7)) << 3)];
                acc[cf] = __builtin_amdgcn_mfma_f32_16x16x32_bf16(av, bv, acc[cf], 0, 0, 0);
            }
        }
        __syncthreads();
    }
    const int rbase = m0 + w * 16 + ((lane >> 4) << 2);
#pragma unroll
    for (int cf = 0; cf < 4; ++cf) {
        const int col = n0 + cf * 16 + (lane & 15);
        const float bb = bias[col];
#pragma unroll
        for (int r = 0; r < 4; ++r)
            out[(size_t)(rbase + r) * DM + col] = f2b(acc[cf][r] + bb);
    }
}

// ---------------------------------------------------------------------------
// 64x64 reg-staged GEMM (XOR swizzle) for N not multiple of 64 (x_proj N=48).
// f32 out.
// ---------------------------------------------------------------------------
__global__ __launch_bounds__(256) void gemm_bf64r(
    const ushort* __restrict__ A, int lda,
    const ushort* __restrict__ W, int ldw,
    float* __restrict__ out, int ldo, int N, int K)
{
    __shared__ __align__(16) ushort As[64 * 64];
    __shared__ __align__(16) ushort Bs[64 * 64];
    const int tid = threadIdx.x;
    const int w = tid >> 6, lane = tid & 63;
    const int m0 = blockIdx.x * 64, n0 = blockIdx.y * 64;
    f32x4 acc[4];
#pragma unroll
    for (int i = 0; i < 4; ++i) acc[i] = (f32x4){0.f, 0.f, 0.f, 0.f};

    for (int k0 = 0; k0 < K; k0 += 64) {
#pragma unroll
        for (int rr = 0; rr < 2; ++rr) {
            const int g = rr * 256 + tid;
            const int row = g >> 3, c8 = g & 7;
            const int phys = row * 64 + ((c8 ^ (row & 7)) << 3);
            *(short8*)&As[phys] = *(const short8*)&A[(size_t)(m0 + row) * lda + k0 + c8 * 8];
            short8 bv = (short8){0,0,0,0,0,0,0,0};
            if (n0 + row < N) bv = *(const short8*)&W[(size_t)(n0 + row) * ldw + k0 + c8 * 8];
            *(short8*)&Bs[phys] = bv;
        }
        __syncthreads();
#pragma unroll
        for (int kk = 0; kk < 2; ++kk) {
            const int row_a = w * 16 + (lane & 15);
            const int c8a = kk * 4 + (lane >> 4);
            const short8 av = *(const short8*)&As[row_a * 64 + ((c8a ^ (row_a & 7)) << 3)];
#pragma unroll
            for (int cf = 0; cf < 4; ++cf) {
                const int row_b = cf * 16 + (lane & 15);
                const short8 bv = *(const short8*)&Bs[row_b * 64 + ((c8a ^ (row_b & 7)) << 3)];
                acc[cf] = __builtin_amdgcn_mfma_f32_16x16x32_bf16(av, bv, acc[cf], 0, 0, 0);
            }
        }
        __syncthreads();
    }
    const int rbase = m0 + w * 16 + ((lane >> 4) << 2);
#pragma unroll
    for (int cf = 0; cf < 4; ++cf) {
        const int col = n0 + cf * 16 + (lane & 15);
        if (col < N) {
#pragma unroll
            for (int r = 0; r < 4; ++r)
                out[(size_t)(rbase + r) * ldo + col] = acc[cf][r];
        }
    }
}

// ---------------------------------------------------------------------------
// LayerNorm over 256 cols (+optional residual add, +gelu, f32/bf16 out)
// ---------------------------------------------------------------------------
__global__ __launch_bounds__(256) void ln_k(
    const float* __restrict__ in, const float* __restrict__ add,
    void* __restrict__ outp,
    const float* __restrict__ s, const float* __restrict__ b,
    int do_gelu, int obf)
{
    const int wid = threadIdx.x >> 6, lane = threadIdx.x & 63;
    const size_t row = blockIdx.x * 4 + wid;
    const size_t base = row * DM + lane * 4;
    const float4 x4 = *(const float4*)&in[base];
    float sum = x4.x + x4.y + x4.z + x4.w;
#pragma unroll
    for (int off = 32; off > 0; off >>= 1) sum += __shfl_xor(sum, off, 64);
    const float mean = sum * 0.00390625f;
    const float d0 = x4.x - mean, d1 = x4.y - mean, d2 = x4.z - mean, d3 = x4.w - mean;
    float vs = d0 * d0 + d1 * d1 + d2 * d2 + d3 * d3;
#pragma unroll
    for (int off = 32; off > 0; off >>= 1) vs += __shfl_xor(vs, off, 64);
    const float rstd = rsqrtf(vs * 0.00390625f + 1e-5f);
    const float4 s4 = *(const float4*)&s[lane * 4];
    const float4 b4 = *(const float4*)&b[lane * 4];
    float o0 = d0 * rstd * s4.x + b4.x;
    float o1 = d1 * rstd * s4.y + b4.y;
    float o2 = d2 * rstd * s4.z + b4.z;
    float o3 = d3 * rstd * s4.w + b4.w;
    if (add) {
        const float4 a4 = *(const float4*)&add[base];
        o0 += a4.x; o1 += a4.y; o2 += a4.z; o3 += a4.w;
    }
    if (do_gelu) { o0 = gelu_f(o0); o1 = gelu_f(o1); o2 = gelu_f(o2); o3 = gelu_f(o3); }
    if (obf) {
        ushort4 r; r.x = f2b(o0); r.y = f2b(o1); r.z = f2b(o2); r.w = f2b(o3);
        *(ushort4*)&((ushort*)outp)[base] = r;
    } else {
        float4 r; r.x = o0; r.y = o1; r.z = o2; r.w = o3;
        *(float4*)&((float*)outp)[base] = r;
    }
}

// ---------------------------------------------------------------------------
__global__ __launch_bounds__(256) void serialize_k(
    const float* __restrict__ x3, const int* __restrict__ inv,
    float* __restrict__ res)
{
    const int wid = threadIdx.x >> 6, lane = threadIdx.x & 63;
    const int r = blockIdx.x * 4 + wid;
    const int b = r / LSEQ, l = r % LSEQ;
    const int o = l >> 12, g = l & 4095;
    const int src = inv[o * NPTS + b * GG + g];
    *(float4*)&res[(size_t)r * DM + lane * 4] = *(const float4*)&x3[(size_t)src * DM + lane * 4];
}

__global__ __launch_bounds__(256) void deserialize_k(
    const float* __restrict__ res, const int* __restrict__ order,
    float* __restrict__ h3)
{
    const int wid = threadIdx.x >> 6, lane = threadIdx.x & 63;
    const int p = blockIdx.x * 4 + wid;
    const int o = p >> 14, n = p & 16383;
    const int m = order[o * NPTS + n];
    const int bp = m >> 12, gp = m & 4095;
    const size_t srow = (size_t)bp * LSEQ + o * GG + gp;
    *(float4*)&h3[(size_t)n * 768 + o * DM + lane * 4] = *(const float4*)&res[srow * DM + lane * 4];
}

// ---------------------------------------------------------------------------
__global__ __launch_bounds__(256) void conv1d_silu_k(
    const ushort* __restrict__ xh, const float* __restrict__ cw,
    const float* __restrict__ cb, ushort* __restrict__ xcb)
{
    const int gidx = blockIdx.x * 256 + threadIdx.x;
    const int t = gidx >> 7;
    const int e4 = (gidx & 127) << 2;
    float wta[4][4];
#pragma unroll
    for (int ee = 0; ee < 4; ++ee) {
        const float4 wv = *(const float4*)&cw[(e4 + ee) * 4];
        wta[ee][0] = wv.x; wta[ee][1] = wv.y; wta[ee][2] = wv.z; wta[ee][3] = wv.w;
    }
    const float4 c4 = *(const float4*)&cb[e4];
    float a[4] = {c4.x, c4.y, c4.z, c4.w};
#pragma unroll
    for (int j = 0; j < 4; ++j) {
        const int tt = t - 3 + j;
        if (tt >= 0) {
            const ushort4 x4 = *(const ushort4*)&xh[(size_t)tt * DI + e4];
            a[0] = fmaf(b2f(x4.x), wta[0][j], a[0]);
            a[1] = fmaf(b2f(x4.y), wta[1][j], a[1]);
            a[2] = fmaf(b2f(x4.z), wta[2][j], a[2]);
            a[3] = fmaf(b2f(x4.w), wta[3][j], a[3]);
        }
    }
    ushort4 rr;
    rr.x = f2b(silu_f(a[0])); rr.y = f2b(silu_f(a[1]));
    rr.z = f2b(silu_f(a[2])); rr.w = f2b(silu_f(a[3]));
    *(ushort4*)&xcb[(size_t)t * DI + e4] = rr;
}

// ---------------------------------------------------------------------------
// Chunked selective scan. Structured-A fast path (A[n] = (n+1)*A[0]).
// ---------------------------------------------------------------------------
__device__ __forceinline__ float dt_dot(const float4* dlt, const float* w, float dtb)
{
    const float4 q0 = dlt[0], q1 = dlt[1], q2 = dlt[2], q3 = dlt[3];
    float s0 = fmaf(q0.x, w[0], dtb);
    float s1 = q0.y * w[1];
    float s2 = q0.z * w[2];
    float s3 = q0.w * w[3];
    s0 = fmaf(q1.x, w[4], s0); s1 = fmaf(q1.y, w[5], s1);
    s2 = fmaf(q1.z, w[6], s2); s3 = fmaf(q1.w, w[7], s3);
    s0 = fmaf(q2.x, w[8], s0); s1 = fmaf(q2.y, w[9], s1);
    s2 = fmaf(q2.z, w[10], s2); s3 = fmaf(q2.w, w[11], s3);
    s0 = fmaf(q3.x, w[12], s0); s1 = fmaf(q3.y, w[13], s1);
    s2 = fmaf(q3.z, w[14], s2); s3 = fmaf(q3.w, w[15], s3);
    return (s0 + s1) + (s2 + s3);
}

__device__ __forceinline__ void pow_table(float e1, float* E)
{
    const float e2 = e1 * e1, e4 = e2 * e2, e8 = e4 * e4;
    E[0] = e1;       E[1] = e2;       E[2] = e2 * e1;  E[3] = e4;
    E[4] = e4 * e1;  E[5] = e4 * e2;  E[6] = E[5] * e1; E[7] = e8;
    E[8] = e8 * e1;  E[9] = e8 * e2;  E[10] = E[9] * e1; E[11] = e8 * e4;
    E[12] = E[11] * e1; E[13] = E[11] * e2; E[14] = E[13] * e1; E[15] = e8 * e8;
}

__global__ __launch_bounds__(256) void scan_pass1_k(
    const ushort* __restrict__ xcb, const float* __restrict__ dbc,
    const float* __restrict__ dtw_all, const float* __restrict__ dtb_all,
    const float* __restrict__ alog_all,
    float* __restrict__ PA, float* __restrict__ HB, int layer)
{
    const int b = blockIdx.y;
    const int ci = blockIdx.x >> 1;
    const int half = blockIdx.x & 1;
    const int e = half * 256 + threadIdx.x;
    float w[DST], A[DST];
    const float* dtw = dtw_all + layer * (DI * DST) + e * DST;
    const float* al  = alog_all + layer * (DI * DST) + e * DST;
#pragma unroll
    for (int r = 0; r < DST; ++r) w[r] = dtw[r];
#pragma unroll
    for (int n = 0; n < DST; ++n) A[n] = -__expf(al[n]);
    bool structA = true;
#pragma unroll
    for (int n = 1; n < DST; ++n)
        structA = structA && (fabsf(A[n] - (n + 1) * A[0]) <= 1e-4f * (n + 1));
    const float lA = A[0] * LOG2E;
    const float dtb = dtb_all[layer * DI + e];
    __shared__ __align__(16) float dl[LCHK][48];
    const int row0 = b * LSEQ + ci * LCHK;
    for (int i = threadIdx.x; i < LCHK * 48; i += 256)
        ((float*)dl)[i] = dbc[(size_t)row0 * 48 + i];
    __syncthreads();
    float h[DST];
#pragma unroll
    for (int n = 0; n < DST; ++n) h[n] = 0.f;
    const size_t off = ((size_t)(b * NCHK + ci) * DI + e) * DST;

    if (structA) {
        float pa1 = 1.f;
        float xc = b2f(xcb[(size_t)row0 * DI + e]);
        for (int t = 0; t < LCHK; ++t) {
            float xn = 0.f;
            if (t + 1 < LCHK) xn = b2f(xcb[(size_t)(row0 + t + 1) * DI + e]);
            const float4* dlt = (const float4*)&dl[t][0];
            const float dt = softplus_fast(dt_dot(dlt, w, dtb));
            const float e1 = exp2f(dt * lA);
            float E[DST];
            pow_table(e1, E);
            const float dx = dt * xc;
            pa1 *= e1;
#pragma unroll
            for (int q = 0; q < 4; ++q) {
                const float4 bq = dlt[4 + q];
                h[4*q+0] = fmaf(h[4*q+0], E[4*q+0], dx * bq.x);
                h[4*q+1] = fmaf(h[4*q+1], E[4*q+1], dx * bq.y);
                h[4*q+2] = fmaf(h[4*q+2], E[4*q+2], dx * bq.z);
                h[4*q+3] = fmaf(h[4*q+3], E[4*q+3], dx * bq.w);
            }
            xc = xn;
        }
        float P[DST];
        pow_table(pa1, P);
#pragma unroll
        for (int n = 0; n < DST; ++n) { PA[off + n] = P[n]; HB[off + n] = h[n]; }
    } else {
        float Alog2[DST], pa[DST];
#pragma unroll
        for (int n = 0; n < DST; ++n) { Alog2[n] = A[n] * LOG2E; pa[n] = 1.f; }
        float xc = b2f(xcb[(size_t)row0 * DI + e]);
        for (int t = 0; t < LCHK; ++t) {
            float xn = 0.f;
            if (t + 1 < LCHK) xn = b2f(xcb[(size_t)(row0 + t + 1) * DI + e]);
            const float4* dlt = (const float4*)&dl[t][0];
            const float dt = softplus_fast(dt_dot(dlt, w, dtb));
            const float dx = dt * xc;
#pragma unroll
            for (int q = 0; q < 4; ++q) {
                const float4 bq = dlt[4 + q];
                const float bb[4] = {bq.x, bq.y, bq.z, bq.w};
#pragma unroll
                for (int j = 0; j < 4; ++j) {
                    const int n = 4*q + j;
                    const float E = exp2f(dt * Alog2[n]);
                    h[n] = fmaf(h[n], E, dx * bb[j]);
                    pa[n] *= E;
                }
            }
            xc = xn;
        }
#pragma unroll
        for (int n = 0; n < DST; ++n) { PA[off + n] = pa[n]; HB[off + n] = h[n]; }
    }
}

__global__ __launch_bounds__(256) void scan_pass2_k(
    const float* __restrict__ PA, float* __restrict__ HB)
{
    const int idx = blockIdx.x * 256 + threadIdx.x;
    const int b = idx >> 13, rem = idx & 8191;
    float h = 0.f;
    for (int ci = 0; ci < NCHK; ++ci) {
        const size_t off = ((size_t)(b * NCHK + ci) << 13) + rem;
        const float pa = PA[off];
        const float hb = HB[off];
        const float nh = fmaf(h, pa, hb);
        HB[off] = h;
        h = nh;
    }
}

__global__ __launch_bounds__(256) void scan_pass3_k(
    const ushort* __restrict__ xcb, const float* __restrict__ dbc,
    const float* __restrict__ dtw_all, const float* __restrict__ dtb_all,
    const float* __restrict__ alog_all, const float* __restrict__ dsk_all,
    const float* __restrict__ HB, ushort* zy, int layer)
{
    const int b = blockIdx.y;
    const int ci = blockIdx.x >> 1;
    const int half = blockIdx.x & 1;
    const int e = half * 256 + threadIdx.x;
    float w[DST], A[DST];
    const float* dtw = dtw_all + layer * (DI * DST) + e * DST;
    const float* al  = alog_all + layer * (DI * DST) + e * DST;
#pragma unroll
    for (int r = 0; r < DST; ++r) w[r] = dtw[r];
#pragma unroll
    for (int n = 0; n < DST; ++n) A[n] = -__expf(al[n]);
    bool structA = true;
#pragma unroll
    for (int n = 1; n < DST; ++n)
        structA = structA && (fabsf(A[n] - (n + 1) * A[0]) <= 1e-4f * (n + 1));
    const float lA = A[0] * LOG2E;
    const float dtb = dtb_all[layer * DI + e];
    const float dsk = dsk_all[layer * DI + e];
    __shared__ __align__(16) float dl[LCHK][48];
    const int row0 = b * LSEQ + ci * LCHK;
    for (int i = threadIdx.x; i < LCHK * 48; i += 256)
        ((float*)dl)[i] = dbc[(size_t)row0 * 48 + i];
    __syncthreads();
    const size_t off = ((size_t)(b * NCHK + ci) * DI + e) * DST;
    float h[DST];
#pragma unroll
    for (int n = 0; n < DST; ++n) h[n] = HB[off + n];
    float xc = b2f(xcb[(size_t)row0 * DI + e]);
    float zc = b2f(zy[(size_t)row0 * DI + e]);

    if (structA) {
        for (int t = 0; t < LCHK; ++t) {
            float xn = 0.f, zn = 0.f;
            if (t + 1 < LCHK) {
                xn = b2f(xcb[(size_t)(row0 + t + 1) * DI + e]);
                zn = b2f(zy[(size_t)(row0 + t + 1) * DI + e]);
            }
            const float4* dlt = (const float4*)&dl[t][0];
            const float dt = softplus_fast(dt_dot(dlt, w, dtb));
            const float e1 = exp2f(dt * lA);
            float E[DST];
            pow_table(e1, E);
            const float dx = dt * xc;
            float y0 = 0.f, y1 = 0.f, y2 = 0.f, y3 = 0.f;
#pragma unroll
            for (int q = 0; q < 4; ++q) {
                const float4 bq = dlt[4 + q];
                const float4 cq = dlt[8 + q];
                h[4*q+0] = fmaf(h[4*q+0], E[4*q+0], dx * bq.x);
                h[4*q+1] = fmaf(h[4*q+1], E[4*q+1], dx * bq.y);
                h[4*q+2] = fmaf(h[4*q+2], E[4*q+2], dx * bq.z);
                h[4*q+3] = fmaf(h[4*q+3], E[4*q+3], dx * bq.w);
                y0 = fmaf(h[4*q+0], cq.x, y0);
                y1 = fmaf(h[4*q+1], cq.y, y1);
                y2 = fmaf(h[4*q+2], cq.z, y2);
                y3 = fmaf(h[4*q+3], cq.w, y3);
            }
            float y = (y0 + y1) + (y2 + y3);
            y = fmaf(xc, dsk, y);
            zy[(size_t)(row0 + t) * DI + e] = f2b(y * silu_f(zc));
            xc = xn; zc = zn;
        }
    } else {
        float Alog2[DST];
#pragma unroll
        for (int n = 0; n < DST; ++n) Alog2[n] = A[n] * LOG2E;
        for (int t = 0; t < LCHK; ++t) {
            float xn = 0.f, zn = 0.f;
            if (t + 1 < LCHK) {
                xn = b2f(xcb[(size_t)(row0 + t + 1) * DI + e]);
                zn = b2f(zy[(size_t)(row0 + t + 1) * DI + e]);
            }
            const float4* dlt = (const float4*)&dl[t][0];
            const float dt = softplus_fast(dt_dot(dlt, w, dtb));
            const float dx = dt * xc;
            float y = 0.f;
#pragma unroll
            for (int q = 0; q < 4; ++q) {
                const float4 bq = dlt[4 + q];
                const float4 cq = dlt[8 + q];
                const float bb[4] = {bq.x, bq.y, bq.z, bq.w};
                const float cc[4] = {cq.x, cq.y, cq.z, cq.w};
#pragma unroll
                for (int j = 0; j < 4; ++j) {
                    const int n = 4*q + j;
                    const float E = exp2f(dt * Alog2[n]);
                    h[n] = fmaf(h[n], E, dx * bb[j]);
                    y = fmaf(h[n], cc[j], y);
                }
            }
            y = fmaf(xc, dsk, y);
            zy[(size_t)(row0 + t) * DI + e] = f2b(y * silu_f(zc));
            xc = xn; zc = zn;
        }
    }
}

// ---------------------------------------------------------------------------
// Launch
// ---------------------------------------------------------------------------
extern "C" void kernel_launch(void* const* d_in, const int* in_sizes, int n_in,
                              void* d_out, int out_size, void* d_ws, size_t ws_size,
                              hipStream_t stream) {
    (void)in_sizes; (void)n_in; (void)out_size; (void)ws_size;
    const float* feat     = (const float*)d_in[0];
    const int*   nidx     = (const int*)d_in[1];
    const int*   order    = (const int*)d_in[2];
    const int*   inv      = (const int*)d_in[3];
    const float* conv_w   = (const float*)d_in[5];
    const float* conv_b   = (const float*)d_in[6];
    const float* cpe_fc_w = (const float*)d_in[7];
    const float* cpe_fc_b = (const float*)d_in[8];
    const float* cpe_ln_s = (const float*)d_in[9];
    const float* cpe_ln_b = (const float*)d_in[10];
    const float* in_proj_w = (const float*)d_in[11];
    const float* conv1d_w  = (const float*)d_in[12];
    const float* conv1d_b  = (const float*)d_in[13];
    const float* x_proj_w  = (const float*)d_in[14];
    const float* dt_proj_w = (const float*)d_in[15];
    const float* dt_proj_b = (const float*)d_in[16];
    const float* A_log     = (const float*)d_in[17];
    const float* D_skip    = (const float*)d_in[18];
    const float* out_proj_w = (const float*)d_in[19];
    const float* blk_ln_s  = (const float*)d_in[20];
    const float* blk_ln_b  = (const float*)d_in[21];
    const float* normf_s   = (const float*)d_in[22];
    const float* normf_b   = (const float*)d_in[23];
    const float* fuse_w1   = (const float*)d_in[24];
    const float* fuse_b1   = (const float*)d_in[25];
    const float* fuse_ln_s = (const float*)d_in[26];
    const float* fuse_ln_b = (const float*)d_in[27];
    const float* fuse_w2   = (const float*)d_in[28];
    const float* fuse_b2   = (const float*)d_in[29];
    float* out = (float*)d_out;
    float* ws = (float*)d_ws;

    // ---- workspace (identical layout to v4/v5; 191.2 MiB) ----
    float* RES   = ws;                          // 12,582,912
    float* ZY    = RES + 12582912;              // 12,582,912
    float* XCBR  = ZY + 12582912;               // 12,582,912
    float* XHB_f = XCBR + 12582912;             //  3,145,728
    float* DBC   = XHB_f + 3145728;             //  2,359,296
    float* PA    = DBC + 2359296;               //  3,145,728
    float* HB    = PA + 3145728;                //  3,145,728
    float* SW    = HB + 3145728;                //    581,632

    ushort* ZY_us = (ushort*)ZY;
    ushort* XCB   = (ushort*)XCBR;
    ushort* HSLB  = XCB + 12582912;
    ushort* FEATB = XCB;
    ushort* W2    = XCB + 4194304;
    ushort* XHB   = (ushort*)XHB_f;
    ushort* SWu   = (ushort*)SW;
    ushort* INWB  = SWu;
    ushort* OUTWB = INWB + 524288;
    ushort* FW1B  = OUTWB + 262144;
    ushort* XPWB  = FW1B + 196608;
    ushort* CPEWB = XPWB + 49152;
    ushort* FW2B  = CPEWB + 65536;

    ushort* X1B = ZY_us;
    float*  X2  = ZY + 2097152;
    float*  X3  = ZY + 6291456;
    float*  H3  = ZY;
    ushort* H3B = XCB;
    float*  F1  = XCBR + 6291456;
    ushort* F2B = (ushort*)(XCBR + 10485760);

    // ---- conversions ----
    f2b_k<<<2048, 256, 0, stream>>>(feat, FEATB, NPTS * DM);
    f2b_k<<<1024, 256, 0, stream>>>(in_proj_w, INWB, 2 * 1024 * DM);
    f2b_k<<<512, 256, 0, stream>>>(out_proj_w, OUTWB, 2 * DM * DI);
    f2b_k<<<512, 256, 0, stream>>>(fuse_w1, FW1B, DM * 768);
    f2b_k<<<128, 256, 0, stream>>>(x_proj_w, XPWB, 2 * 48 * DI);
    f2b_k<<<256, 256, 0, stream>>>(cpe_fc_w, CPEWB, DM * DM);
    f2b_k<<<256, 256, 0, stream>>>(fuse_w2, FW2B, DM * DM);
    transpose_convw_k<<<dim3(KNB * DM / 32, DM / 32), 256, 0, stream>>>(conv_w, W2);

    // ---- CPE ----
    gather_bf<<<dim3(NPTS / 64, DM / 64), 256, 0, stream>>>(FEATB, nidx, W2, conv_b, X1B);
    gemm_bf64g<<<dim3(NPTS / 64, DM / 64), 256, 0, stream>>>(X1B, DM, CPEWB, DM, cpe_fc_b,
                                                             X2, DM, DM);
    ln_k<<<NPTS / 4, 256, 0, stream>>>(X2, feat, X3, cpe_ln_s, cpe_ln_b, 0, 0);
    serialize_k<<<SEQ / 4, 256, 0, stream>>>(X3, inv, RES);

    // ---- Mamba blocks ----
    for (int l = 0; l < 2; ++l) {
        ln_k<<<SEQ / 4, 256, 0, stream>>>(RES, nullptr, HSLB,
                                          blk_ln_s + l * DM, blk_ln_b + l * DM, 0, 1);
        for (int b = 0; b < BB; ++b) {
            gemm_bf128<<<dim3(LSEQ / 128, 8), 256, 0, stream>>>(
                HSLB + (size_t)b * LSEQ * DM, DM, INWB + l * 262144, DM,
                XHB, DI, ZY_us + (size_t)b * LSEQ * DI, DI, 512, DM, 2);
            conv1d_silu_k<<<LSEQ * 128 / 256, 256, 0, stream>>>(
                XHB, conv1d_w + l * 2048, conv1d_b + l * DI,
                XCB + (size_t)b * LSEQ * DI);
        }
        gemm_bf64r<<<dim3(SEQ / 64, 1), 256, 0, stream>>>(
            XCB, DI, XPWB + l * 24576, DI, DBC, 48, 48, DI);
        scan_pass1_k<<<dim3(NCHK * 2, BB), 256, 0, stream>>>(
            XCB, DBC, dt_proj_w, dt_proj_b, A_log, PA, HB, l);
        scan_pass2_k<<<128, 256, 0, stream>>>(PA, HB);
        scan_pass3_k<<<dim3(NCHK * 2, BB), 256, 0, stream>>>(
            XCB, DBC, dt_proj_w, dt_proj_b, A_log, D_skip, HB, ZY_us, l);
        gemm_bf128<<<dim3(SEQ / 128, 2), 256, 0, stream>>>(
            ZY_us, DI, OUTWB + l * 131072, DI,
            RES, DM, nullptr, 0, 1 << 30, DI, 1);
    }

    // ---- Final: deserialize -> rowwise LN -> fuse MLP ----
    deserialize_k<<<SEQ / 4, 256, 0, stream>>>(RES, order, H3);
    ln_k<<<SEQ / 4, 256, 0, stream>>>(H3, nullptr, H3B, normf_s, normf_b, 0, 1);
    gemm_bf64g<<<dim3(NPTS / 64, DM / 64), 256, 0, stream>>>(H3B, 768, FW1B, 768, fuse_b1,
                                                             F1, DM, 768);
    ln_k<<<NPTS / 4, 256, 0, stream>>>(F1, nullptr, F2B, fuse_ln_s, fuse_ln_b, 1, 1);
    gemm_bf64g<<<dim3(NPTS / 64, DM / 64), 256, 0, stream>>>(F2B, DM, FW2B, DM, fuse_b2,
                                                             out, DM, DM);
}